// Round 1
// baseline (2720.746 us; speedup 1.0000x reference)
//
#include <hip/hip_runtime.h>
#include <hip/hip_bf16.h>

#define NH 16
#define HD 64
#define T_SEQ 2048
#define DM 1024

typedef __attribute__((ext_vector_type(8))) short short8;

static __device__ __forceinline__ float bf2f(short u) {
    unsigned int x = ((unsigned int)(unsigned short)u) << 16;
    union { unsigned int i; float f; } c; c.i = x; return c.f;
}

// ---------------- Kernel 1: QKV GEMM (f32 in, bf16 head-layout out) ----------------
// C[m][n] = sum_k X[m][k] * W[k][n] + bias[n];  M=8192, N=3072, K=1024
// n -> (which = n/1024, h = (n%1024)/64, d = n%64); m -> (b = m/2048, t = m%2048)
// store to (Q|K|V)[((b*16+h)*2048 + t)*64 + d]  (bf16)
__global__ __launch_bounds__(256) void qkv_gemm(
    const float* __restrict__ X, const float* __restrict__ W, const float* __restrict__ bias,
    __hip_bfloat16* __restrict__ Qb, __hip_bfloat16* __restrict__ Kb, __hip_bfloat16* __restrict__ Vb)
{
    const int N = 3 * DM;
    __shared__ float As[16][64];
    __shared__ float Bs[16][64];
    const int tid = threadIdx.x;
    const int tx = tid & 15, ty = tid >> 4;
    const int m0 = blockIdx.y * 64;
    const int n0 = blockIdx.x * 64;

    float acc[4][4] = {};
    for (int k0 = 0; k0 < DM; k0 += 16) {
        #pragma unroll
        for (int j = 0; j < 4; ++j) {
            int lin = tid + 256 * j;
            int kk = lin & 15, m = lin >> 4;
            As[kk][m] = X[(size_t)(m0 + m) * DM + k0 + kk];
        }
        #pragma unroll
        for (int j = 0; j < 4; ++j) {
            int lin = tid + 256 * j;
            int n = lin & 63, kk = lin >> 6;
            Bs[kk][n] = W[(size_t)(k0 + kk) * N + n0 + n];
        }
        __syncthreads();
        #pragma unroll
        for (int kk = 0; kk < 16; ++kk) {
            float a[4], b[4];
            #pragma unroll
            for (int i = 0; i < 4; ++i) a[i] = As[kk][ty * 4 + i];
            #pragma unroll
            for (int j = 0; j < 4; ++j) b[j] = Bs[kk][tx * 4 + j];
            #pragma unroll
            for (int i = 0; i < 4; ++i)
                #pragma unroll
                for (int j = 0; j < 4; ++j)
                    acc[i][j] += a[i] * b[j];
        }
        __syncthreads();
    }

    const int which = n0 >> 10;
    const int h = (n0 & 1023) >> 6;
    __hip_bfloat16* dst = (which == 0) ? Qb : ((which == 1) ? Kb : Vb);
    #pragma unroll
    for (int i = 0; i < 4; ++i) {
        int m = m0 + ty * 4 + i;
        int b = m >> 11, t = m & 2047;
        size_t rowbase = (((size_t)(b * NH + h)) * T_SEQ + t) * HD;
        #pragma unroll
        for (int j = 0; j < 4; ++j) {
            float v = acc[i][j] + bias[n0 + tx * 4 + j];
            dst[rowbase + tx * 4 + j] = __float2bfloat16(v);
        }
    }
}

// ---------------- Kernel 2: causal flash attention (f32 accumulate) ----------------
// One thread per q row. Block = 256 rows of one (b,h). K/V tiles of 64 rows in LDS (f32).
__global__ __launch_bounds__(256) void attn(
    const __hip_bfloat16* __restrict__ Qb, const __hip_bfloat16* __restrict__ Kb,
    const __hip_bfloat16* __restrict__ Vb, __hip_bfloat16* __restrict__ AO)
{
    __shared__ float Ks[64][64];
    __shared__ float Vs[64][64];
    const int bh = blockIdx.y;            // b*16 + h
    const int q0 = blockIdx.x * 256;
    const int q  = q0 + threadIdx.x;

    // load q row (scaled)
    float qreg[64];
    {
        const size_t gq = ((size_t)bh * T_SEQ + q) * HD;
        #pragma unroll
        for (int s = 0; s < 8; ++s) {
            short8 v = *(const short8*)(Qb + gq + s * 8);
            #pragma unroll
            for (int j = 0; j < 8; ++j) qreg[s * 8 + j] = bf2f(v[j]) * 0.125f;
        }
    }

    float mrun = -INFINITY, lrun = 0.f;
    float acc[64] = {};

    const int row = threadIdx.x >> 2;
    const int seg = (threadIdx.x & 3) * 16;
    const int ntiles = (q0 >> 6) + 4;

    for (int td = 0; td < ntiles; ++td) {
        const int base = td * 64;
        const size_t g = ((size_t)bh * T_SEQ + base + row) * HD + seg;
        short8 k0 = *(const short8*)(Kb + g);
        short8 k1 = *(const short8*)(Kb + g + 8);
        short8 v0 = *(const short8*)(Vb + g);
        short8 v1 = *(const short8*)(Vb + g + 8);
        __syncthreads();   // previous tile fully consumed
        {
            float4 f;
            f.x = bf2f(k0[0]); f.y = bf2f(k0[1]); f.z = bf2f(k0[2]); f.w = bf2f(k0[3]);
            *(float4*)&Ks[row][seg + 0] = f;
            f.x = bf2f(k0[4]); f.y = bf2f(k0[5]); f.z = bf2f(k0[6]); f.w = bf2f(k0[7]);
            *(float4*)&Ks[row][seg + 4] = f;
            f.x = bf2f(k1[0]); f.y = bf2f(k1[1]); f.z = bf2f(k1[2]); f.w = bf2f(k1[3]);
            *(float4*)&Ks[row][seg + 8] = f;
            f.x = bf2f(k1[4]); f.y = bf2f(k1[5]); f.z = bf2f(k1[6]); f.w = bf2f(k1[7]);
            *(float4*)&Ks[row][seg + 12] = f;
            f.x = bf2f(v0[0]); f.y = bf2f(v0[1]); f.z = bf2f(v0[2]); f.w = bf2f(v0[3]);
            *(float4*)&Vs[row][seg + 0] = f;
            f.x = bf2f(v0[4]); f.y = bf2f(v0[5]); f.z = bf2f(v0[6]); f.w = bf2f(v0[7]);
            *(float4*)&Vs[row][seg + 4] = f;
            f.x = bf2f(v1[0]); f.y = bf2f(v1[1]); f.z = bf2f(v1[2]); f.w = bf2f(v1[3]);
            *(float4*)&Vs[row][seg + 8] = f;
            f.x = bf2f(v1[4]); f.y = bf2f(v1[5]); f.z = bf2f(v1[6]); f.w = bf2f(v1[7]);
            *(float4*)&Vs[row][seg + 12] = f;
        }
        __syncthreads();

        const int kend = min(64, q - base + 1);
        for (int kk = 0; kk < kend; ++kk) {
            float s0 = 0.f, s1 = 0.f, s2 = 0.f, s3 = 0.f;
            #pragma unroll
            for (int d = 0; d < 64; d += 4) {
                s0 += qreg[d + 0] * Ks[kk][d + 0];
                s1 += qreg[d + 1] * Ks[kk][d + 1];
                s2 += qreg[d + 2] * Ks[kk][d + 2];
                s3 += qreg[d + 3] * Ks[kk][d + 3];
            }
            float s = (s0 + s1) + (s2 + s3);
            if (s > mrun) {
                float corr = __expf(mrun - s);   // exp(-inf)=0 on first hit
                lrun *= corr;
                #pragma unroll
                for (int d = 0; d < 64; ++d) acc[d] *= corr;
                mrun = s;
            }
            float p = __expf(s - mrun);
            lrun += p;
            #pragma unroll
            for (int d = 0; d < 64; ++d) acc[d] += p * Vs[kk][d];
        }
    }

    const float inv = 1.f / lrun;
    const int b = bh >> 4, h = bh & 15;
    const size_t o = ((size_t)(b * T_SEQ + q)) * DM + h * HD;
    #pragma unroll
    for (int d = 0; d < 64; ++d) AO[o + d] = __float2bfloat16(acc[d] * inv);
}

// ---------------- Kernel 3: output projection (bf16 A, f32 W/out) ----------------
__global__ __launch_bounds__(256) void proj_gemm(
    const __hip_bfloat16* __restrict__ A, const float* __restrict__ W,
    const float* __restrict__ bias, float* __restrict__ Y)
{
    __shared__ float As[16][64];
    __shared__ float Bs[16][64];
    const int tid = threadIdx.x;
    const int tx = tid & 15, ty = tid >> 4;
    const int m0 = blockIdx.y * 64;
    const int n0 = blockIdx.x * 64;

    float acc[4][4] = {};
    for (int k0 = 0; k0 < DM; k0 += 16) {
        #pragma unroll
        for (int j = 0; j < 4; ++j) {
            int lin = tid + 256 * j;
            int kk = lin & 15, m = lin >> 4;
            As[kk][m] = __bfloat162float(A[(size_t)(m0 + m) * DM + k0 + kk]);
        }
        #pragma unroll
        for (int j = 0; j < 4; ++j) {
            int lin = tid + 256 * j;
            int n = lin & 63, kk = lin >> 6;
            Bs[kk][n] = W[(size_t)(k0 + kk) * DM + n0 + n];
        }
        __syncthreads();
        #pragma unroll
        for (int kk = 0; kk < 16; ++kk) {
            float a[4], b[4];
            #pragma unroll
            for (int i = 0; i < 4; ++i) a[i] = As[kk][ty * 4 + i];
            #pragma unroll
            for (int j = 0; j < 4; ++j) b[j] = Bs[kk][tx * 4 + j];
            #pragma unroll
            for (int i = 0; i < 4; ++i)
                #pragma unroll
                for (int j = 0; j < 4; ++j)
                    acc[i][j] += a[i] * b[j];
        }
        __syncthreads();
    }
    #pragma unroll
    for (int i = 0; i < 4; ++i) {
        int m = m0 + ty * 4 + i;
        #pragma unroll
        for (int j = 0; j < 4; ++j) {
            int n = n0 + tx * 4 + j;
            Y[(size_t)m * DM + n] = acc[i][j] + bias[n];
        }
    }
}

extern "C" void kernel_launch(void* const* d_in, const int* in_sizes, int n_in,
                              void* d_out, int out_size, void* d_ws, size_t ws_size,
                              hipStream_t stream) {
    const float* x      = (const float*)d_in[0];
    const float* W_qkv  = (const float*)d_in[1];
    const float* b_qkv  = (const float*)d_in[2];
    const float* W_proj = (const float*)d_in[3];
    const float* b_proj = (const float*)d_in[4];
    float* out = (float*)d_out;

    const size_t perbuf = (size_t)4 * NH * T_SEQ * HD;   // 8,388,608 elems
    __hip_bfloat16* Qb = (__hip_bfloat16*)d_ws;
    __hip_bfloat16* Kb = Qb + perbuf;
    __hip_bfloat16* Vb = Kb + perbuf;
    __hip_bfloat16* AO = Vb + perbuf;                    // [8192][1024] bf16

    // QKV: M=8192 N=3072
    hipLaunchKernelGGL(qkv_gemm, dim3(3 * DM / 64, 8192 / 64), dim3(256), 0, stream,
                       x, W_qkv, b_qkv, Qb, Kb, Vb);
    // Attention: 8 q-blocks x 64 (b,h)
    hipLaunchKernelGGL(attn, dim3(T_SEQ / 256, 4 * NH), dim3(256), 0, stream,
                       Qb, Kb, Vb, AO);
    // Proj: M=8192 N=1024
    hipLaunchKernelGGL(proj_gemm, dim3(DM / 64, 8192 / 64), dim3(256), 0, stream,
                       AO, W_proj, b_proj, out);
}

// Round 2
// 1307.384 us; speedup vs baseline: 2.0811x; 2.0811x over previous
//
#include <hip/hip_runtime.h>
#include <hip/hip_bf16.h>

#define NH 16
#define HD 64
#define T_SEQ 2048
#define DM 1024

typedef __attribute__((ext_vector_type(8))) short short8;
typedef __attribute__((ext_vector_type(4))) float f32x4;
typedef unsigned short ushort;

static __device__ __forceinline__ float bf2f(short u) {
    unsigned int x = ((unsigned int)(unsigned short)u) << 16;
    union { unsigned int i; float f; } c; c.i = x; return c.f;
}
static __device__ __forceinline__ ushort f2bf(float f) {
    union { float f; unsigned int u; } c; c.f = f;
    unsigned int r = (c.u + 0x7fffu + ((c.u >> 16) & 1u)) >> 16;
    return (ushort)r;
}

// ---------------- Kernel 1: QKV GEMM (f32 in, bf16 out; Q scaled, V transposed) ----------------
__global__ __launch_bounds__(256) void qkv_gemm(
    const float* __restrict__ X, const float* __restrict__ W, const float* __restrict__ bias,
    ushort* __restrict__ Qb, ushort* __restrict__ Kb, ushort* __restrict__ Vt)
{
    const int N = 3 * DM;
    __shared__ float As[16][64];
    __shared__ float Bs[16][64];
    const int tid = threadIdx.x;
    const int tx = tid & 15, ty = tid >> 4;
    const int m0 = blockIdx.y * 64;
    const int n0 = blockIdx.x * 64;

    float acc[4][4] = {};
    for (int k0 = 0; k0 < DM; k0 += 16) {
        #pragma unroll
        for (int j = 0; j < 4; ++j) {
            int lin = tid + 256 * j;
            int kk = lin & 15, m = lin >> 4;
            As[kk][m] = X[(size_t)(m0 + m) * DM + k0 + kk];
        }
        #pragma unroll
        for (int j = 0; j < 4; ++j) {
            int lin = tid + 256 * j;
            int n = lin & 63, kk = lin >> 6;
            Bs[kk][n] = W[(size_t)(k0 + kk) * N + n0 + n];
        }
        __syncthreads();
        #pragma unroll
        for (int kk = 0; kk < 16; ++kk) {
            float a[4], b[4];
            #pragma unroll
            for (int i = 0; i < 4; ++i) a[i] = As[kk][ty * 4 + i];
            #pragma unroll
            for (int j = 0; j < 4; ++j) b[j] = Bs[kk][tx * 4 + j];
            #pragma unroll
            for (int i = 0; i < 4; ++i)
                #pragma unroll
                for (int j = 0; j < 4; ++j)
                    acc[i][j] += a[i] * b[j];
        }
        __syncthreads();
    }

    const int which = n0 >> 10;
    const int h = (n0 & 1023) >> 6;
    if (which == 2) {
        // V: store transposed per head: Vt[(bh*64 + d)*2048 + t]
        #pragma unroll
        for (int i = 0; i < 4; ++i) {
            int m = m0 + ty * 4 + i;
            int b = m >> 11, t = m & 2047;
            size_t base = ((size_t)(b * NH + h)) * HD;
            #pragma unroll
            for (int j = 0; j < 4; ++j) {
                float v = acc[i][j] + bias[n0 + tx * 4 + j];
                Vt[(base + tx * 4 + j) * T_SEQ + t] = f2bf(v);
            }
        }
    } else {
        ushort* dst = (which == 0) ? Qb : Kb;
        const float sc = (which == 0) ? 0.125f : 1.0f;   // 1/sqrt(64) folded into Q
        #pragma unroll
        for (int i = 0; i < 4; ++i) {
            int m = m0 + ty * 4 + i;
            int b = m >> 11, t = m & 2047;
            size_t rowbase = (((size_t)(b * NH + h)) * T_SEQ + t) * HD;
            #pragma unroll
            for (int j = 0; j < 4; ++j) {
                float v = (acc[i][j] + bias[n0 + tx * 4 + j]) * sc;
                dst[rowbase + tx * 4 + j] = f2bf(v);
            }
        }
    }
}

// ---------------- Kernel 2: MFMA causal flash attention ----------------
// Block: 4 waves, 128 q-rows (wave w: rows q0+w*32 .. +31), one (b,h).
// KV tiles of 64. QK^T and PV via mfma_f32_16x16x32_bf16.
__global__ __launch_bounds__(256) void attn_mfma(
    const ushort* __restrict__ Qb,   // [bh][t][64], pre-scaled by 1/8
    const ushort* __restrict__ Kb,   // [bh][t][64]
    const ushort* __restrict__ Vt,   // [bh][d][2048]
    ushort* __restrict__ AO)         // [b*2048 + t][1024] bf16
{
    __shared__ __align__(16) ushort Ks[64 * 64];
    __shared__ __align__(16) ushort Vs[64 * 64];   // [d][k], swizzled
    __shared__ __align__(16) ushort Ps[4][32 * 64];

    const int bh = blockIdx.y;
    const int q0 = blockIdx.x * 128;
    const int tid = threadIdx.x;
    const int wid = tid >> 6;
    const int lane = tid & 63;
    const int lr = lane & 15;
    const int g = lane >> 4;

    const int qlo = q0 + wid * 32;

    const ushort* Kg = Kb + (size_t)bh * T_SEQ * HD;
    const ushort* Vg = Vt + (size_t)bh * HD * T_SEQ;

    // Q fragments: qf[qi][ks] = A-frag rows (qlo+qi*16+lr), d = ks*32 + g*8 ..+8
    short8 qf[2][2];
    {
        const ushort* Qg = Qb + ((size_t)bh * T_SEQ + qlo) * HD;
        #pragma unroll
        for (int qi = 0; qi < 2; ++qi)
            #pragma unroll
            for (int ks = 0; ks < 2; ++ks)
                qf[qi][ks] = *(const short8*)(Qg + (size_t)(qi * 16 + lr) * HD + ks * 32 + g * 8);
    }

    f32x4 acc[2][4] = {};
    float mrun[2][4], lrun[2][4];
    #pragma unroll
    for (int qi = 0; qi < 2; ++qi)
        #pragma unroll
        for (int r = 0; r < 4; ++r) { mrun[qi][r] = -INFINITY; lrun[qi][r] = 0.f; }

    ushort* Psw = Ps[wid];
    const int ntiles = q0 / 64 + 2;

    for (int tt = 0; tt < ntiles; ++tt) {
        const int k0 = tt * 64;
        __syncthreads();   // previous tile fully consumed
        #pragma unroll
        for (int c0 = 0; c0 < 512; c0 += 256) {
            int c = c0 + tid;
            int row = c >> 3, co = (c & 7) * 8;
            int sw = co ^ ((row & 7) << 3);
            short8 kv = *(const short8*)(Kg + (size_t)(k0 + row) * HD + co);
            *(short8*)(&Ks[row * 64 + sw]) = kv;
            short8 vv = *(const short8*)(Vg + (size_t)row * T_SEQ + k0 + co);
            *(short8*)(&Vs[row * 64 + sw]) = vv;
        }
        __syncthreads();

        if (k0 > qlo + 31) continue;   // fully masked for this wave (no more barriers below)

        // ---- QK^T: S[32 q][64 k]
        f32x4 s[2][4] = {};
        #pragma unroll
        for (int ks = 0; ks < 2; ++ks) {
            #pragma unroll
            for (int ki = 0; ki < 4; ++ki) {
                int krow = ki * 16 + lr;
                short8 kf = *(const short8*)(&Ks[krow * 64 + ((ks * 32 + g * 8) ^ ((krow & 7) << 3))]);
                s[0][ki] = __builtin_amdgcn_mfma_f32_16x16x32_bf16(qf[0][ks], kf, s[0][ki], 0, 0, 0);
                s[1][ki] = __builtin_amdgcn_mfma_f32_16x16x32_bf16(qf[1][ks], kf, s[1][ki], 0, 0, 0);
            }
        }

        const bool needmask = (k0 + 63 > qlo);

        // ---- online softmax (rows live in 16-lane groups; row = qi*16 + g*4 + r, col = lr)
        #pragma unroll
        for (int qi = 0; qi < 2; ++qi) {
            #pragma unroll
            for (int r = 0; r < 4; ++r) {
                float s0 = s[qi][0][r], s1 = s[qi][1][r], s2 = s[qi][2][r], s3 = s[qi][3][r];
                if (needmask) {
                    const int qrow = qlo + qi * 16 + g * 4 + r;
                    const int kc = k0 + lr;
                    s0 = (kc      <= qrow) ? s0 : -INFINITY;
                    s1 = (kc + 16 <= qrow) ? s1 : -INFINITY;
                    s2 = (kc + 32 <= qrow) ? s2 : -INFINITY;
                    s3 = (kc + 48 <= qrow) ? s3 : -INFINITY;
                }
                float tmax = fmaxf(fmaxf(s0, s1), fmaxf(s2, s3));
                tmax = fmaxf(tmax, __shfl_xor(tmax, 1));
                tmax = fmaxf(tmax, __shfl_xor(tmax, 2));
                tmax = fmaxf(tmax, __shfl_xor(tmax, 4));
                tmax = fmaxf(tmax, __shfl_xor(tmax, 8));
                const float mold = mrun[qi][r];
                const float mnew = fmaxf(mold, tmax);
                const float corr = __expf(mold - mnew);
                float p0 = __expf(s0 - mnew), p1 = __expf(s1 - mnew);
                float p2 = __expf(s2 - mnew), p3 = __expf(s3 - mnew);
                float rs = (p0 + p1) + (p2 + p3);
                rs += __shfl_xor(rs, 1);
                rs += __shfl_xor(rs, 2);
                rs += __shfl_xor(rs, 4);
                rs += __shfl_xor(rs, 8);
                lrun[qi][r] = lrun[qi][r] * corr + rs;
                mrun[qi][r] = mnew;
                #pragma unroll
                for (int di = 0; di < 4; ++di) acc[qi][di][r] *= corr;
                // P -> LDS (bf16, swizzled), layout [q 32][k 64]
                const int prow = qi * 16 + g * 4 + r;
                ushort* pw = &Psw[prow * 64];
                const int sw8 = (prow & 7) << 3;
                pw[(lr)      ^ sw8] = f2bf(p0);
                pw[(16 + lr) ^ sw8] = f2bf(p1);
                pw[(32 + lr) ^ sw8] = f2bf(p2);
                pw[(48 + lr) ^ sw8] = f2bf(p3);
            }
        }

        // ---- PV: acc[32 q][64 d] += P[32 q][64 k] * V[64 k][64 d]
        #pragma unroll
        for (int ks = 0; ks < 2; ++ks) {
            const int koff = ks * 32 + g * 8;
            short8 pf0, pf1;
            {
                int prow = lr;
                pf0 = *(const short8*)(&Psw[prow * 64 + (koff ^ ((prow & 7) << 3))]);
                prow = 16 + lr;
                pf1 = *(const short8*)(&Psw[prow * 64 + (koff ^ ((prow & 7) << 3))]);
            }
            #pragma unroll
            for (int di = 0; di < 4; ++di) {
                int vrow = di * 16 + lr;
                short8 vf = *(const short8*)(&Vs[vrow * 64 + (koff ^ ((vrow & 7) << 3))]);
                acc[0][di] = __builtin_amdgcn_mfma_f32_16x16x32_bf16(pf0, vf, acc[0][di], 0, 0, 0);
                acc[1][di] = __builtin_amdgcn_mfma_f32_16x16x32_bf16(pf1, vf, acc[1][di], 0, 0, 0);
            }
        }
    }

    // ---- epilogue: O = acc / l, store bf16 at [b*2048+t][h*64+d]
    const int b = bh >> 4, h = bh & 15;
    ushort* AOg = AO + (size_t)b * T_SEQ * DM + h * HD;
    #pragma unroll
    for (int qi = 0; qi < 2; ++qi) {
        #pragma unroll
        for (int r = 0; r < 4; ++r) {
            const float inv = 1.f / lrun[qi][r];
            const int qrow = qlo + qi * 16 + g * 4 + r;
            #pragma unroll
            for (int di = 0; di < 4; ++di)
                AOg[(size_t)qrow * DM + di * 16 + lr] = f2bf(acc[qi][di][r] * inv);
        }
    }
}

// ---------------- Kernel 3: output projection (bf16 A, f32 W/out) ----------------
__global__ __launch_bounds__(256) void proj_gemm(
    const ushort* __restrict__ A, const float* __restrict__ W,
    const float* __restrict__ bias, float* __restrict__ Y)
{
    __shared__ float As[16][64];
    __shared__ float Bs[16][64];
    const int tid = threadIdx.x;
    const int tx = tid & 15, ty = tid >> 4;
    const int m0 = blockIdx.y * 64;
    const int n0 = blockIdx.x * 64;

    float acc[4][4] = {};
    for (int k0 = 0; k0 < DM; k0 += 16) {
        #pragma unroll
        for (int j = 0; j < 4; ++j) {
            int lin = tid + 256 * j;
            int kk = lin & 15, m = lin >> 4;
            As[kk][m] = bf2f((short)A[(size_t)(m0 + m) * DM + k0 + kk]);
        }
        #pragma unroll
        for (int j = 0; j < 4; ++j) {
            int lin = tid + 256 * j;
            int n = lin & 63, kk = lin >> 6;
            Bs[kk][n] = W[(size_t)(k0 + kk) * DM + n0 + n];
        }
        __syncthreads();
        #pragma unroll
        for (int kk = 0; kk < 16; ++kk) {
            float a[4], b[4];
            #pragma unroll
            for (int i = 0; i < 4; ++i) a[i] = As[kk][ty * 4 + i];
            #pragma unroll
            for (int j = 0; j < 4; ++j) b[j] = Bs[kk][tx * 4 + j];
            #pragma unroll
            for (int i = 0; i < 4; ++i)
                #pragma unroll
                for (int j = 0; j < 4; ++j)
                    acc[i][j] += a[i] * b[j];
        }
        __syncthreads();
    }
    #pragma unroll
    for (int i = 0; i < 4; ++i) {
        int m = m0 + ty * 4 + i;
        #pragma unroll
        for (int j = 0; j < 4; ++j) {
            int n = n0 + tx * 4 + j;
            Y[(size_t)m * DM + n] = acc[i][j] + bias[n];
        }
    }
}

extern "C" void kernel_launch(void* const* d_in, const int* in_sizes, int n_in,
                              void* d_out, int out_size, void* d_ws, size_t ws_size,
                              hipStream_t stream) {
    const float* x      = (const float*)d_in[0];
    const float* W_qkv  = (const float*)d_in[1];
    const float* b_qkv  = (const float*)d_in[2];
    const float* W_proj = (const float*)d_in[3];
    const float* b_proj = (const float*)d_in[4];
    float* out = (float*)d_out;

    const size_t perbuf = (size_t)4 * NH * T_SEQ * HD;   // 8,388,608 elems
    ushort* Qb = (ushort*)d_ws;
    ushort* Kb = Qb + perbuf;
    ushort* Vt = Kb + perbuf;                            // transposed V [bh][d][t]
    ushort* AO = Vt + perbuf;                            // [8192][1024] bf16

    hipLaunchKernelGGL(qkv_gemm, dim3(3 * DM / 64, 8192 / 64), dim3(256), 0, stream,
                       x, W_qkv, b_qkv, Qb, Kb, Vt);
    hipLaunchKernelGGL(attn_mfma, dim3(T_SEQ / 128, 4 * NH), dim3(256), 0, stream,
                       Qb, Kb, Vt, AO);
    hipLaunchKernelGGL(proj_gemm, dim3(DM / 64, 8192 / 64), dim3(256), 0, stream,
                       AO, W_proj, b_proj, out);
}

// Round 4
// 361.188 us; speedup vs baseline: 7.5328x; 3.6197x over previous
//
#include <hip/hip_runtime.h>
#include <hip/hip_bf16.h>

#define NH 16
#define HD 64
#define T_SEQ 2048
#define DM 1024

typedef __attribute__((ext_vector_type(8))) short short8;
typedef __attribute__((ext_vector_type(4))) short sh4;
typedef __attribute__((ext_vector_type(4))) float f32x4;
typedef unsigned short ushort;

static __device__ __forceinline__ float bf2f(short u) {
    unsigned int x = ((unsigned int)(unsigned short)u) << 16;
    union { unsigned int i; float f; } c; c.i = x; return c.f;
}
static __device__ __forceinline__ ushort f2bf(float f) {
    union { float f; unsigned int u; } c; c.f = f;
    unsigned int r = (c.u + 0x7fffu + ((c.u >> 16) & 1u)) >> 16;
    return (ushort)r;
}

// ---------------- conversion: f32 -> bf16 (vectorized) ----------------
__global__ __launch_bounds__(256) void conv_bf16(const float* __restrict__ src,
                                                 ushort* __restrict__ dst) {
    int i = blockIdx.x * 256 + threadIdx.x;
    const float* s = src + (size_t)i * 8;
    float4 a = *(const float4*)(s);
    float4 b = *(const float4*)(s + 4);
    short8 o;
    o[0] = f2bf(a.x); o[1] = f2bf(a.y); o[2] = f2bf(a.z); o[3] = f2bf(a.w);
    o[4] = f2bf(b.x); o[5] = f2bf(b.y); o[6] = f2bf(b.z); o[7] = f2bf(b.w);
    *(short8*)(dst + (size_t)i * 8) = o;
}

// ---------------- transpose + convert: W[1024][N] f32 -> Wt[N][1024] bf16 ----------------
__global__ __launch_bounds__(256) void transpose_w(const float* __restrict__ W,
                                                   ushort* __restrict__ Wt, int N) {
    __shared__ float Ts[64][65];
    const int n0 = blockIdx.x * 64, k0 = blockIdx.y * 64;
    const int tid = threadIdx.x;
    const int cg = tid & 15, r4 = tid >> 4;
    #pragma unroll
    for (int i = 0; i < 4; ++i) {
        int r = r4 + i * 16;
        float4 v = *(const float4*)(W + (size_t)(k0 + r) * N + n0 + cg * 4);
        Ts[r][cg * 4 + 0] = v.x; Ts[r][cg * 4 + 1] = v.y;
        Ts[r][cg * 4 + 2] = v.z; Ts[r][cg * 4 + 3] = v.w;
    }
    __syncthreads();
    #pragma unroll
    for (int i = 0; i < 4; ++i) {
        int r = r4 + i * 16;
        sh4 o;
        o[0] = (short)f2bf(Ts[cg * 4 + 0][r]);
        o[1] = (short)f2bf(Ts[cg * 4 + 1][r]);
        o[2] = (short)f2bf(Ts[cg * 4 + 2][r]);
        o[3] = (short)f2bf(Ts[cg * 4 + 3][r]);
        *(sh4*)(Wt + (size_t)(n0 + r) * DM + k0 + cg * 4) = o;
    }
}

// ---------------- MFMA GEMM core: C[128m][128n] = A[m][k] * Bt[n][k]^T, K=1024 ----------------
// 4 waves (2x2), each 64x64 = 4x4 frags of 16x16x32. LDS XOR-swizzled (slot ^= row&7).
static __device__ __forceinline__ void gemm_core(
    const ushort* __restrict__ A, const ushort* __restrict__ Bt,
    ushort* __restrict__ As, ushort* __restrict__ Bs,
    int m0, int n0, f32x4 acc[4][4])
{
    const int tid = threadIdx.x;
    const int wid = tid >> 6, lane = tid & 63;
    const int lr = lane & 15, g = lane >> 4;
    const int wm = wid >> 1, wn = wid & 1;

    int cdst[4];
    #pragma unroll
    for (int i = 0; i < 4; ++i) {
        int c = i * 256 + tid;
        int row = c >> 3, slot = c & 7;
        cdst[i] = row * 64 + ((slot ^ (row & 7)) * 8);
    }

    short8 la[4], lb[4];
    #pragma unroll
    for (int i = 0; i < 4; ++i) {
        int c = i * 256 + tid; int row = c >> 3, slot = c & 7;
        la[i] = *(const short8*)(A + (size_t)(m0 + row) * DM + slot * 8);
        lb[i] = *(const short8*)(Bt + (size_t)(n0 + row) * DM + slot * 8);
    }

    for (int kt = 0; kt < 16; ++kt) {
        __syncthreads();
        #pragma unroll
        for (int i = 0; i < 4; ++i) {
            *(short8*)(As + cdst[i]) = la[i];
            *(short8*)(Bs + cdst[i]) = lb[i];
        }
        __syncthreads();
        if (kt < 15) {
            const int k0 = (kt + 1) * 64;
            #pragma unroll
            for (int i = 0; i < 4; ++i) {
                int c = i * 256 + tid; int row = c >> 3, slot = c & 7;
                la[i] = *(const short8*)(A + (size_t)(m0 + row) * DM + k0 + slot * 8);
                lb[i] = *(const short8*)(Bt + (size_t)(n0 + row) * DM + k0 + slot * 8);
            }
        }
        #pragma unroll
        for (int ks = 0; ks < 2; ++ks) {
            short8 af[4], bfr[4];
            #pragma unroll
            for (int mi = 0; mi < 4; ++mi) {
                int row = wm * 64 + mi * 16 + lr;
                af[mi] = *(const short8*)(As + row * 64 + (((ks * 4 + g) ^ (row & 7)) * 8));
            }
            #pragma unroll
            for (int ni = 0; ni < 4; ++ni) {
                int row = wn * 64 + ni * 16 + lr;
                bfr[ni] = *(const short8*)(Bs + row * 64 + (((ks * 4 + g) ^ (row & 7)) * 8));
            }
            #pragma unroll
            for (int mi = 0; mi < 4; ++mi)
                #pragma unroll
                for (int ni = 0; ni < 4; ++ni)
                    acc[mi][ni] = __builtin_amdgcn_mfma_f32_16x16x32_bf16(af[mi], bfr[ni], acc[mi][ni], 0, 0, 0);
        }
    }
}

// ---------------- Kernel 1: QKV GEMM (MFMA), scatter Q/K head-major, V transposed ----------------
__global__ __launch_bounds__(256) void qkv_mfma(
    const ushort* __restrict__ Xb, const ushort* __restrict__ Wqt,
    const float* __restrict__ bias,
    ushort* __restrict__ Qb, ushort* __restrict__ Kb, ushort* __restrict__ Vt)
{
    __shared__ __align__(16) ushort smem[16384];
    ushort* As = smem; ushort* Bs = smem + 8192;
    const int m0 = blockIdx.y * 128;
    const int n0 = blockIdx.x * 128;
    f32x4 acc[4][4] = {};
    gemm_core(Xb, Wqt, As, Bs, m0, n0, acc);

    const int tid = threadIdx.x;
    const int wid = tid >> 6, lane = tid & 63;
    const int lr = lane & 15, g = lane >> 4;
    const int wm = wid >> 1, wn = wid & 1;
    const int which = n0 >> 10;
    const int bq = m0 >> 11;

    if (which < 2) {
        ushort* dst = which ? Kb : Qb;
        const float sc = which ? 1.0f : 0.125f;   // fold 1/sqrt(64) into Q
        #pragma unroll
        for (int ni = 0; ni < 4; ++ni) {
            int nn = n0 + wn * 64 + ni * 16 + lr;
            const float bv = bias[nn];
            const int hh = (nn & 1023) >> 6, dd = nn & 63;
            const size_t hb = ((size_t)(bq * NH + hh)) * T_SEQ;
            #pragma unroll
            for (int mi = 0; mi < 4; ++mi)
                #pragma unroll
                for (int r = 0; r < 4; ++r) {
                    int t = (m0 + wm * 64 + mi * 16 + g * 4 + r) & 2047;
                    dst[(hb + t) * HD + dd] = f2bf((acc[mi][ni][r] + bv) * sc);
                }
        }
    } else {
        // V: transpose via LDS, store Vt[(bq*1024 + nloc)][t] coalesced
        __syncthreads();
        ushort* Ct = smem;   // 128x128 bf16 = 32 KB
        #pragma unroll
        for (int ni = 0; ni < 4; ++ni) {
            int lcol = wn * 64 + ni * 16 + lr;
            const float bv = bias[n0 + lcol];
            #pragma unroll
            for (int mi = 0; mi < 4; ++mi)
                #pragma unroll
                for (int r = 0; r < 4; ++r)
                    Ct[(wm * 64 + mi * 16 + g * 4 + r) * 128 + lcol] = f2bf(acc[mi][ni][r] + bv);
        }
        __syncthreads();
        const int dloc = tid >> 1, th = (tid & 1) * 64;
        const int nn = (n0 & 1023) + dloc;
        ushort* dst = Vt + ((size_t)(bq * 1024 + nn)) * T_SEQ + (m0 & 2047) + th;
        #pragma unroll
        for (int e8 = 0; e8 < 8; ++e8) {
            short8 v;
            #pragma unroll
            for (int u = 0; u < 8; ++u) v[u] = (short)Ct[(th + e8 * 8 + u) * 128 + dloc];
            *(short8*)(dst + e8 * 8) = v;
        }
    }
}

// ---------------- Kernel 3: output projection (MFMA), f32 out + bias ----------------
__global__ __launch_bounds__(256) void proj_mfma(
    const ushort* __restrict__ AO, const ushort* __restrict__ Wpt,
    const float* __restrict__ bias, float* __restrict__ Y)
{
    __shared__ __align__(16) ushort smem[16384];
    const int m0 = blockIdx.y * 128;
    const int n0 = blockIdx.x * 128;
    f32x4 acc[4][4] = {};
    gemm_core(AO, Wpt, smem, smem + 8192, m0, n0, acc);

    const int tid = threadIdx.x;
    const int wid = tid >> 6, lane = tid & 63;
    const int lr = lane & 15, g = lane >> 4;
    const int wm = wid >> 1, wn = wid & 1;
    #pragma unroll
    for (int ni = 0; ni < 4; ++ni) {
        int nn = n0 + wn * 64 + ni * 16 + lr;
        const float bv = bias[nn];
        #pragma unroll
        for (int mi = 0; mi < 4; ++mi)
            #pragma unroll
            for (int r = 0; r < 4; ++r) {
                int m = m0 + wm * 64 + mi * 16 + g * 4 + r;
                Y[(size_t)m * DM + nn] = acc[mi][ni][r] + bv;
            }
    }
}

// ---------------- Kernel 2: MFMA causal flash attention (unchanged from R2) ----------------
__global__ __launch_bounds__(256) void attn_mfma(
    const ushort* __restrict__ Qb,   // [bh][t][64], pre-scaled by 1/8
    const ushort* __restrict__ Kb,   // [bh][t][64]
    const ushort* __restrict__ Vt,   // [bh][d][2048]
    ushort* __restrict__ AO)         // [b*2048 + t][1024] bf16
{
    __shared__ __align__(16) ushort Ks[64 * 64];
    __shared__ __align__(16) ushort Vs[64 * 64];
    __shared__ __align__(16) ushort Ps[4][32 * 64];

    const int bh = blockIdx.y;
    const int q0 = blockIdx.x * 128;
    const int tid = threadIdx.x;
    const int wid = tid >> 6;
    const int lane = tid & 63;
    const int lr = lane & 15;
    const int g = lane >> 4;

    const int qlo = q0 + wid * 32;

    const ushort* Kg = Kb + (size_t)bh * T_SEQ * HD;
    const ushort* Vg = Vt + (size_t)bh * HD * T_SEQ;

    short8 qf[2][2];
    {
        const ushort* Qg = Qb + ((size_t)bh * T_SEQ + qlo) * HD;
        #pragma unroll
        for (int qi = 0; qi < 2; ++qi)
            #pragma unroll
            for (int ks = 0; ks < 2; ++ks)
                qf[qi][ks] = *(const short8*)(Qg + (size_t)(qi * 16 + lr) * HD + ks * 32 + g * 8);
    }

    f32x4 acc[2][4] = {};
    float mrun[2][4], lrun[2][4];
    #pragma unroll
    for (int qi = 0; qi < 2; ++qi)
        #pragma unroll
        for (int r = 0; r < 4; ++r) { mrun[qi][r] = -INFINITY; lrun[qi][r] = 0.f; }

    ushort* Psw = Ps[wid];
    const int ntiles = q0 / 64 + 2;

    for (int tt = 0; tt < ntiles; ++tt) {
        const int k0 = tt * 64;
        __syncthreads();
        #pragma unroll
        for (int c0 = 0; c0 < 512; c0 += 256) {
            int c = c0 + tid;
            int row = c >> 3, co = (c & 7) * 8;
            int sw = co ^ ((row & 7) << 3);
            short8 kv = *(const short8*)(Kg + (size_t)(k0 + row) * HD + co);
            *(short8*)(&Ks[row * 64 + sw]) = kv;
            short8 vv = *(const short8*)(Vg + (size_t)row * T_SEQ + k0 + co);
            *(short8*)(&Vs[row * 64 + sw]) = vv;
        }
        __syncthreads();

        if (k0 > qlo + 31) continue;

        f32x4 s[2][4] = {};
        #pragma unroll
        for (int ks = 0; ks < 2; ++ks) {
            #pragma unroll
            for (int ki = 0; ki < 4; ++ki) {
                int krow = ki * 16 + lr;
                short8 kf = *(const short8*)(&Ks[krow * 64 + ((ks * 32 + g * 8) ^ ((krow & 7) << 3))]);
                s[0][ki] = __builtin_amdgcn_mfma_f32_16x16x32_bf16(qf[0][ks], kf, s[0][ki], 0, 0, 0);
                s[1][ki] = __builtin_amdgcn_mfma_f32_16x16x32_bf16(qf[1][ks], kf, s[1][ki], 0, 0, 0);
            }
        }

        const bool needmask = (k0 + 63 > qlo);

        #pragma unroll
        for (int qi = 0; qi < 2; ++qi) {
            #pragma unroll
            for (int r = 0; r < 4; ++r) {
                float s0 = s[qi][0][r], s1 = s[qi][1][r], s2 = s[qi][2][r], s3 = s[qi][3][r];
                if (needmask) {
                    const int qrow = qlo + qi * 16 + g * 4 + r;
                    const int kc = k0 + lr;
                    s0 = (kc      <= qrow) ? s0 : -INFINITY;
                    s1 = (kc + 16 <= qrow) ? s1 : -INFINITY;
                    s2 = (kc + 32 <= qrow) ? s2 : -INFINITY;
                    s3 = (kc + 48 <= qrow) ? s3 : -INFINITY;
                }
                float tmax = fmaxf(fmaxf(s0, s1), fmaxf(s2, s3));
                tmax = fmaxf(tmax, __shfl_xor(tmax, 1));
                tmax = fmaxf(tmax, __shfl_xor(tmax, 2));
                tmax = fmaxf(tmax, __shfl_xor(tmax, 4));
                tmax = fmaxf(tmax, __shfl_xor(tmax, 8));
                const float mold = mrun[qi][r];
                const float mnew = fmaxf(mold, tmax);
                const float corr = __expf(mold - mnew);
                float p0 = __expf(s0 - mnew), p1 = __expf(s1 - mnew);
                float p2 = __expf(s2 - mnew), p3 = __expf(s3 - mnew);
                float rs = (p0 + p1) + (p2 + p3);
                rs += __shfl_xor(rs, 1);
                rs += __shfl_xor(rs, 2);
                rs += __shfl_xor(rs, 4);
                rs += __shfl_xor(rs, 8);
                lrun[qi][r] = lrun[qi][r] * corr + rs;
                mrun[qi][r] = mnew;
                #pragma unroll
                for (int di = 0; di < 4; ++di) acc[qi][di][r] *= corr;
                const int prow = qi * 16 + g * 4 + r;
                ushort* pw = &Psw[prow * 64];
                const int sw8 = (prow & 7) << 3;
                pw[(lr)      ^ sw8] = f2bf(p0);
                pw[(16 + lr) ^ sw8] = f2bf(p1);
                pw[(32 + lr) ^ sw8] = f2bf(p2);
                pw[(48 + lr) ^ sw8] = f2bf(p3);
            }
        }

        #pragma unroll
        for (int ks = 0; ks < 2; ++ks) {
            const int koff = ks * 32 + g * 8;
            short8 pf0, pf1;
            {
                int prow = lr;
                pf0 = *(const short8*)(&Psw[prow * 64 + (koff ^ ((prow & 7) << 3))]);
                prow = 16 + lr;
                pf1 = *(const short8*)(&Psw[prow * 64 + (koff ^ ((prow & 7) << 3))]);
            }
            #pragma unroll
            for (int di = 0; di < 4; ++di) {
                int vrow = di * 16 + lr;
                short8 vf = *(const short8*)(&Vs[vrow * 64 + (koff ^ ((vrow & 7) << 3))]);
                acc[0][di] = __builtin_amdgcn_mfma_f32_16x16x32_bf16(pf0, vf, acc[0][di], 0, 0, 0);
                acc[1][di] = __builtin_amdgcn_mfma_f32_16x16x32_bf16(pf1, vf, acc[1][di], 0, 0, 0);
            }
        }
    }

    const int b = bh >> 4, h = bh & 15;
    ushort* AOg = AO + (size_t)b * T_SEQ * DM + h * HD;
    #pragma unroll
    for (int qi = 0; qi < 2; ++qi) {
        #pragma unroll
        for (int r = 0; r < 4; ++r) {
            const float inv = 1.f / lrun[qi][r];
            const int qrow = qlo + qi * 16 + g * 4 + r;
            #pragma unroll
            for (int di = 0; di < 4; ++di)
                AOg[(size_t)qrow * DM + di * 16 + lr] = f2bf(acc[qi][di][r] * inv);
        }
    }
}

extern "C" void kernel_launch(void* const* d_in, const int* in_sizes, int n_in,
                              void* d_out, int out_size, void* d_ws, size_t ws_size,
                              hipStream_t stream) {
    const float* x      = (const float*)d_in[0];
    const float* W_qkv  = (const float*)d_in[1];
    const float* b_qkv  = (const float*)d_in[2];
    const float* W_proj = (const float*)d_in[3];
    const float* b_proj = (const float*)d_in[4];
    float* out = (float*)d_out;

    const size_t perbuf = (size_t)4 * NH * T_SEQ * HD;   // 8,388,608 elems
    ushort* Qb  = (ushort*)d_ws;
    ushort* Kb  = Qb + perbuf;
    ushort* Vt  = Kb + perbuf;
    ushort* AO  = Vt + perbuf;           // attn output (written after Wqt is dead)
    ushort* Wqt = AO;                    // alias: consumed by qkv_mfma before attn writes AO
    ushort* Wpt = Qb;                    // alias: written after attn consumed Qb
    ushort* Xb  = (ushort*)d_out;        // alias: d_out used as scratch, overwritten by proj

    // X -> bf16 (8.4M elems, 8 per thread)
    hipLaunchKernelGGL(conv_bf16, dim3(4096), dim3(256), 0, stream, x, Xb);
    // W_qkv^T -> bf16 [3072][1024]
    hipLaunchKernelGGL(transpose_w, dim3(48, 16), dim3(256), 0, stream, W_qkv, Wqt, 3 * DM);
    // QKV GEMM
    hipLaunchKernelGGL(qkv_mfma, dim3(24, 64), dim3(256), 0, stream,
                       Xb, Wqt, b_qkv, Qb, Kb, Vt);
    // Attention
    hipLaunchKernelGGL(attn_mfma, dim3(T_SEQ / 128, 4 * NH), dim3(256), 0, stream,
                       Qb, Kb, Vt, AO);
    // W_proj^T -> bf16 [1024][1024] (into Qb slot, now dead)
    hipLaunchKernelGGL(transpose_w, dim3(16, 16), dim3(256), 0, stream, W_proj, Wpt, DM);
    // Projection
    hipLaunchKernelGGL(proj_mfma, dim3(8, 64), dim3(256), 0, stream,
                       AO, Wpt, b_proj, out);
}

// Round 5
// 300.928 us; speedup vs baseline: 9.0412x; 1.2002x over previous
//
#include <hip/hip_runtime.h>
#include <hip/hip_bf16.h>

#define NH 16
#define HD 64
#define T_SEQ 2048
#define DM 1024

typedef __attribute__((ext_vector_type(8))) short short8;
typedef __attribute__((ext_vector_type(4))) short sh4;
typedef __attribute__((ext_vector_type(4))) float f32x4;
typedef unsigned short ushort;

static __device__ __forceinline__ float bf2f(short u) {
    unsigned int x = ((unsigned int)(unsigned short)u) << 16;
    union { unsigned int i; float f; } c; c.i = x; return c.f;
}
static __device__ __forceinline__ ushort f2bf(float f) {
    union { float f; unsigned int u; } c; c.f = f;
    unsigned int r = (c.u + 0x7fffu + ((c.u >> 16) & 1u)) >> 16;
    return (ushort)r;
}

// ---------------- conversion: f32 -> bf16 (vectorized) ----------------
__global__ __launch_bounds__(256) void conv_bf16(const float* __restrict__ src,
                                                 ushort* __restrict__ dst) {
    int i = blockIdx.x * 256 + threadIdx.x;
    const float* s = src + (size_t)i * 8;
    float4 a = *(const float4*)(s);
    float4 b = *(const float4*)(s + 4);
    short8 o;
    o[0] = f2bf(a.x); o[1] = f2bf(a.y); o[2] = f2bf(a.z); o[3] = f2bf(a.w);
    o[4] = f2bf(b.x); o[5] = f2bf(b.y); o[6] = f2bf(b.z); o[7] = f2bf(b.w);
    *(short8*)(dst + (size_t)i * 8) = o;
}

// ---------------- transpose + convert: W[1024][N] f32 -> Wt[N][1024] bf16 ----------------
__global__ __launch_bounds__(256) void transpose_w(const float* __restrict__ W,
                                                   ushort* __restrict__ Wt, int N) {
    __shared__ float Ts[64][65];
    const int n0 = blockIdx.x * 64, k0 = blockIdx.y * 64;
    const int tid = threadIdx.x;
    const int cg = tid & 15, r4 = tid >> 4;
    #pragma unroll
    for (int i = 0; i < 4; ++i) {
        int r = r4 + i * 16;
        float4 v = *(const float4*)(W + (size_t)(k0 + r) * N + n0 + cg * 4);
        Ts[r][cg * 4 + 0] = v.x; Ts[r][cg * 4 + 1] = v.y;
        Ts[r][cg * 4 + 2] = v.z; Ts[r][cg * 4 + 3] = v.w;
    }
    __syncthreads();
    #pragma unroll
    for (int i = 0; i < 4; ++i) {
        int r = r4 + i * 16;
        sh4 o;
        o[0] = (short)f2bf(Ts[cg * 4 + 0][r]);
        o[1] = (short)f2bf(Ts[cg * 4 + 1][r]);
        o[2] = (short)f2bf(Ts[cg * 4 + 2][r]);
        o[3] = (short)f2bf(Ts[cg * 4 + 3][r]);
        *(sh4*)(Wt + (size_t)(n0 + r) * DM + k0 + cg * 4) = o;
    }
}

// ---------------- MFMA GEMM core (unchanged from R4) ----------------
static __device__ __forceinline__ void gemm_core(
    const ushort* __restrict__ A, const ushort* __restrict__ Bt,
    ushort* __restrict__ As, ushort* __restrict__ Bs,
    int m0, int n0, f32x4 acc[4][4])
{
    const int tid = threadIdx.x;
    const int wid = tid >> 6, lane = tid & 63;
    const int lr = lane & 15, g = lane >> 4;
    const int wm = wid >> 1, wn = wid & 1;

    int cdst[4];
    #pragma unroll
    for (int i = 0; i < 4; ++i) {
        int c = i * 256 + tid;
        int row = c >> 3, slot = c & 7;
        cdst[i] = row * 64 + ((slot ^ (row & 7)) * 8);
    }

    short8 la[4], lb[4];
    #pragma unroll
    for (int i = 0; i < 4; ++i) {
        int c = i * 256 + tid; int row = c >> 3, slot = c & 7;
        la[i] = *(const short8*)(A + (size_t)(m0 + row) * DM + slot * 8);
        lb[i] = *(const short8*)(Bt + (size_t)(n0 + row) * DM + slot * 8);
    }

    for (int kt = 0; kt < 16; ++kt) {
        __syncthreads();
        #pragma unroll
        for (int i = 0; i < 4; ++i) {
            *(short8*)(As + cdst[i]) = la[i];
            *(short8*)(Bs + cdst[i]) = lb[i];
        }
        __syncthreads();
        if (kt < 15) {
            const int k0 = (kt + 1) * 64;
            #pragma unroll
            for (int i = 0; i < 4; ++i) {
                int c = i * 256 + tid; int row = c >> 3, slot = c & 7;
                la[i] = *(const short8*)(A + (size_t)(m0 + row) * DM + k0 + slot * 8);
                lb[i] = *(const short8*)(Bt + (size_t)(n0 + row) * DM + k0 + slot * 8);
            }
        }
        #pragma unroll
        for (int ks = 0; ks < 2; ++ks) {
            short8 af[4], bfr[4];
            #pragma unroll
            for (int mi = 0; mi < 4; ++mi) {
                int row = wm * 64 + mi * 16 + lr;
                af[mi] = *(const short8*)(As + row * 64 + (((ks * 4 + g) ^ (row & 7)) * 8));
            }
            #pragma unroll
            for (int ni = 0; ni < 4; ++ni) {
                int row = wn * 64 + ni * 16 + lr;
                bfr[ni] = *(const short8*)(Bs + row * 64 + (((ks * 4 + g) ^ (row & 7)) * 8));
            }
            #pragma unroll
            for (int mi = 0; mi < 4; ++mi)
                #pragma unroll
                for (int ni = 0; ni < 4; ++ni)
                    acc[mi][ni] = __builtin_amdgcn_mfma_f32_16x16x32_bf16(af[mi], bfr[ni], acc[mi][ni], 0, 0, 0);
        }
    }
}

// ---------------- Kernel 1: QKV GEMM (unchanged from R4) ----------------
__global__ __launch_bounds__(256) void qkv_mfma(
    const ushort* __restrict__ Xb, const ushort* __restrict__ Wqt,
    const float* __restrict__ bias,
    ushort* __restrict__ Qb, ushort* __restrict__ Kb, ushort* __restrict__ Vt)
{
    __shared__ __align__(16) ushort smem[16384];
    ushort* As = smem; ushort* Bs = smem + 8192;
    const int m0 = blockIdx.y * 128;
    const int n0 = blockIdx.x * 128;
    f32x4 acc[4][4] = {};
    gemm_core(Xb, Wqt, As, Bs, m0, n0, acc);

    const int tid = threadIdx.x;
    const int wid = tid >> 6, lane = tid & 63;
    const int lr = lane & 15, g = lane >> 4;
    const int wm = wid >> 1, wn = wid & 1;
    const int which = n0 >> 10;
    const int bq = m0 >> 11;

    if (which < 2) {
        ushort* dst = which ? Kb : Qb;
        const float sc = which ? 1.0f : 0.125f;
        #pragma unroll
        for (int ni = 0; ni < 4; ++ni) {
            int nn = n0 + wn * 64 + ni * 16 + lr;
            const float bv = bias[nn];
            const int hh = (nn & 1023) >> 6, dd = nn & 63;
            const size_t hb = ((size_t)(bq * NH + hh)) * T_SEQ;
            #pragma unroll
            for (int mi = 0; mi < 4; ++mi)
                #pragma unroll
                for (int r = 0; r < 4; ++r) {
                    int t = (m0 + wm * 64 + mi * 16 + g * 4 + r) & 2047;
                    dst[(hb + t) * HD + dd] = f2bf((acc[mi][ni][r] + bv) * sc);
                }
        }
    } else {
        __syncthreads();
        ushort* Ct = smem;
        #pragma unroll
        for (int ni = 0; ni < 4; ++ni) {
            int lcol = wn * 64 + ni * 16 + lr;
            const float bv = bias[n0 + lcol];
            #pragma unroll
            for (int mi = 0; mi < 4; ++mi)
                #pragma unroll
                for (int r = 0; r < 4; ++r)
                    Ct[(wm * 64 + mi * 16 + g * 4 + r) * 128 + lcol] = f2bf(acc[mi][ni][r] + bv);
        }
        __syncthreads();
        const int dloc = tid >> 1, th = (tid & 1) * 64;
        const int nn = (n0 & 1023) + dloc;
        ushort* dst = Vt + ((size_t)(bq * 1024 + nn)) * T_SEQ + (m0 & 2047) + th;
        #pragma unroll
        for (int e8 = 0; e8 < 8; ++e8) {
            short8 v;
            #pragma unroll
            for (int u = 0; u < 8; ++u) v[u] = (short)Ct[(th + e8 * 8 + u) * 128 + dloc];
            *(short8*)(dst + e8 * 8) = v;
        }
    }
}

// ---------------- Kernel 3: output projection (unchanged from R4) ----------------
__global__ __launch_bounds__(256) void proj_mfma(
    const ushort* __restrict__ AO, const ushort* __restrict__ Wpt,
    const float* __restrict__ bias, float* __restrict__ Y)
{
    __shared__ __align__(16) ushort smem[16384];
    const int m0 = blockIdx.y * 128;
    const int n0 = blockIdx.x * 128;
    f32x4 acc[4][4] = {};
    gemm_core(AO, Wpt, smem, smem + 8192, m0, n0, acc);

    const int tid = threadIdx.x;
    const int wid = tid >> 6, lane = tid & 63;
    const int lr = lane & 15, g = lane >> 4;
    const int wm = wid >> 1, wn = wid & 1;
    #pragma unroll
    for (int ni = 0; ni < 4; ++ni) {
        int nn = n0 + wn * 64 + ni * 16 + lr;
        const float bv = bias[nn];
        #pragma unroll
        for (int mi = 0; mi < 4; ++mi)
            #pragma unroll
            for (int r = 0; r < 4; ++r) {
                int m = m0 + wm * 64 + mi * 16 + g * 4 + r;
                Y[(size_t)m * DM + nn] = acc[mi][ni][r] + bv;
            }
    }
}

// ---------------- Kernel 2: swapped-QK^T MFMA flash attention ----------------
// S^T = mfma(K, Q): lane holds 16 P-values for ONE q-row -> lane-local softmax.
// PV as O^T = mfma(V^T, P^T): P^T B-frags built in-register (cvt_pk + shfl).
__global__ __launch_bounds__(256) void attn_mfma(
    const ushort* __restrict__ Qb,   // [bh][t][64], pre-scaled by 1/8
    const ushort* __restrict__ Kb,   // [bh][t][64]
    const ushort* __restrict__ Vt,   // [bh][d][2048]
    ushort* __restrict__ AO)         // [b*2048 + t][1024] bf16
{
    __shared__ __align__(16) ushort Ks[64 * 64];
    __shared__ __align__(16) ushort Vs[64 * 64];   // [d][k], swizzled

    const int bh = blockIdx.y;
    const int q0 = (15 - blockIdx.x) * 128;        // heavy-first dispatch
    const int tid = threadIdx.x;
    const int wid = tid >> 6;
    const int lane = tid & 63;
    const int lr = lane & 15;
    const int g = lane >> 4;

    const int qlo = q0 + wid * 32;

    const ushort* Kg = Kb + (size_t)bh * T_SEQ * HD;
    const ushort* Vg = Vt + (size_t)bh * HD * T_SEQ;

    // Q fragments (B-operand): qb[qi][ks] holds Q[q=qlo+qi*16+lr][d=ks*32+g*8..+8]
    short8 qb[2][2];
    {
        const ushort* Qg = Qb + ((size_t)bh * T_SEQ + qlo) * HD;
        #pragma unroll
        for (int qi = 0; qi < 2; ++qi)
            #pragma unroll
            for (int ks = 0; ks < 2; ++ks)
                qb[qi][ks] = *(const short8*)(Qg + (size_t)(qi * 16 + lr) * HD + ks * 32 + g * 8);
    }

    f32x4 po[2][4] = {};          // O^T accum: po[qi][di][r] = O^T[16di+4g+r][qlo+16qi+lr]
    float mrun[2] = {-INFINITY, -INFINITY};
    float lrun[2] = {0.f, 0.f};

    const int srcA = ((lane >> 4) & 1) * 32 + lr;   // 2*(g&1)*16 + lr
    const int srcB = srcA + 16;
    const bool selhi = (lane >> 5) != 0;            // g >= 2

    const int ntiles = q0 / 64 + 2;

    for (int tt = 0; tt < ntiles; ++tt) {
        const int k0 = tt * 64;
        __syncthreads();   // previous tile fully consumed
        #pragma unroll
        for (int c0 = 0; c0 < 512; c0 += 256) {
            int c = c0 + tid;
            int row = c >> 3, co = (c & 7) * 8;
            int sw = co ^ ((row & 7) << 3);
            short8 kv = *(const short8*)(Kg + (size_t)(k0 + row) * HD + co);
            *(short8*)(&Ks[row * 64 + sw]) = kv;
            short8 vv = *(const short8*)(Vg + (size_t)row * T_SEQ + k0 + co);
            *(short8*)(&Vs[row * 64 + sw]) = vv;
        }
        __syncthreads();

        if (k0 > qlo + 31) continue;   // fully masked for this wave

        // ---- S^T[64 k][32 q] = mfma(K, Q)
        f32x4 sp[2][4] = {};   // [qi][ki]; sp[qi][ki][r] = S[k0+16ki+4g+r][qlo+16qi+lr]
        #pragma unroll
        for (int ks = 0; ks < 2; ++ks) {
            #pragma unroll
            for (int ki = 0; ki < 4; ++ki) {
                int krow = ki * 16 + lr;
                short8 kf = *(const short8*)(&Ks[krow * 64 + ((ks * 32 + g * 8) ^ ((krow & 7) << 3))]);
                sp[0][ki] = __builtin_amdgcn_mfma_f32_16x16x32_bf16(kf, qb[0][ks], sp[0][ki], 0, 0, 0);
                sp[1][ki] = __builtin_amdgcn_mfma_f32_16x16x32_bf16(kf, qb[1][ks], sp[1][ki], 0, 0, 0);
            }
        }

        const bool needmask = (k0 + 63 > qlo);

        #pragma unroll
        for (int qi = 0; qi < 2; ++qi) {
            const int q = qlo + qi * 16 + lr;
            // ---- causal mask
            if (needmask) {
                const int lim = q - k0 - 4 * g;
                #pragma unroll
                for (int ki = 0; ki < 4; ++ki)
                    #pragma unroll
                    for (int r = 0; r < 4; ++r)
                        sp[qi][ki][r] = (ki * 16 + r <= lim) ? sp[qi][ki][r] : -INFINITY;
            }
            // ---- lane-local softmax (16 values; row spans 4 lanes g=0..3 at same lr)
            float tmax = -INFINITY;
            #pragma unroll
            for (int ki = 0; ki < 4; ++ki)
                #pragma unroll
                for (int r = 0; r < 4; ++r) tmax = fmaxf(tmax, sp[qi][ki][r]);
            tmax = fmaxf(tmax, __shfl_xor(tmax, 16));
            tmax = fmaxf(tmax, __shfl_xor(tmax, 32));
            const float mold = mrun[qi];
            const float mnew = fmaxf(mold, tmax);
            const float corr = __expf(mold - mnew);
            float rs = 0.f;
            #pragma unroll
            for (int ki = 0; ki < 4; ++ki)
                #pragma unroll
                for (int r = 0; r < 4; ++r) {
                    float p = __expf(sp[qi][ki][r] - mnew);
                    sp[qi][ki][r] = p;
                    rs += p;
                }
            rs += __shfl_xor(rs, 16);
            rs += __shfl_xor(rs, 32);
            lrun[qi] = lrun[qi] * corr + rs;
            mrun[qi] = mnew;
            #pragma unroll
            for (int di = 0; di < 4; ++di)
                #pragma unroll
                for (int r = 0; r < 4; ++r) po[qi][di][r] *= corr;
        }

        // ---- repack P^T into PV B-frags (in-register) and accumulate O^T
        #pragma unroll
        for (int qi = 0; qi < 2; ++qi) {
            unsigned int u[4][2];
            #pragma unroll
            for (int ki = 0; ki < 4; ++ki) {
                asm("v_cvt_pk_bf16_f32 %0, %1, %2"
                    : "=v"(u[ki][0]) : "v"(sp[qi][ki][0]), "v"(sp[qi][ki][1]));
                asm("v_cvt_pk_bf16_f32 %0, %1, %2"
                    : "=v"(u[ki][1]) : "v"(sp[qi][ki][2]), "v"(sp[qi][ki][3]));
            }
            #pragma unroll
            for (int ks = 0; ks < 2; ++ks) {
                const int a0 = (int)u[2 * ks][0],     a1 = (int)u[2 * ks][1];
                const int b0 = (int)u[2 * ks + 1][0], b1 = (int)u[2 * ks + 1][1];
                const int lo0 = __shfl(a0, srcA), lo1 = __shfl(a1, srcA);
                const int lo2 = __shfl(a0, srcB), lo3 = __shfl(a1, srcB);
                const int hi0 = __shfl(b0, srcA), hi1 = __shfl(b1, srcA);
                const int hi2 = __shfl(b0, srcB), hi3 = __shfl(b1, srcB);
                union { int w[4]; short8 s8; } pb;
                pb.w[0] = selhi ? hi0 : lo0;
                pb.w[1] = selhi ? hi1 : lo1;
                pb.w[2] = selhi ? hi2 : lo2;
                pb.w[3] = selhi ? hi3 : lo3;
                const int koff = (ks * 32 + g * 8);
                #pragma unroll
                for (int di = 0; di < 4; ++di) {
                    int vrow = di * 16 + lr;
                    short8 vf = *(const short8*)(&Vs[vrow * 64 + (koff ^ ((vrow & 7) << 3))]);
                    po[qi][di] = __builtin_amdgcn_mfma_f32_16x16x32_bf16(vf, pb.s8, po[qi][di], 0, 0, 0);
                }
            }
        }
    }

    // ---- epilogue: O = O^T / l, packed b64 stores
    const int b = bh >> 4, h = bh & 15;
    ushort* AOg = AO + (size_t)b * T_SEQ * DM + h * HD;
    #pragma unroll
    for (int qi = 0; qi < 2; ++qi) {
        const float inv = 1.f / lrun[qi];
        const int q = qlo + qi * 16 + lr;
        #pragma unroll
        for (int di = 0; di < 4; ++di) {
            unsigned int w0, w1;
            float f0 = po[qi][di][0] * inv, f1 = po[qi][di][1] * inv;
            float f2 = po[qi][di][2] * inv, f3 = po[qi][di][3] * inv;
            asm("v_cvt_pk_bf16_f32 %0, %1, %2" : "=v"(w0) : "v"(f0), "v"(f1));
            asm("v_cvt_pk_bf16_f32 %0, %1, %2" : "=v"(w1) : "v"(f2), "v"(f3));
            uint2 wv; wv.x = w0; wv.y = w1;
            *(uint2*)(AOg + (size_t)q * DM + di * 16 + g * 4) = wv;
        }
    }
}

extern "C" void kernel_launch(void* const* d_in, const int* in_sizes, int n_in,
                              void* d_out, int out_size, void* d_ws, size_t ws_size,
                              hipStream_t stream) {
    const float* x      = (const float*)d_in[0];
    const float* W_qkv  = (const float*)d_in[1];
    const float* b_qkv  = (const float*)d_in[2];
    const float* W_proj = (const float*)d_in[3];
    const float* b_proj = (const float*)d_in[4];
    float* out = (float*)d_out;

    const size_t perbuf = (size_t)4 * NH * T_SEQ * HD;
    ushort* Qb  = (ushort*)d_ws;
    ushort* Kb  = Qb + perbuf;
    ushort* Vt  = Kb + perbuf;
    ushort* AO  = Vt + perbuf;
    ushort* Wqt = AO;                    // consumed by qkv_mfma before attn writes AO
    ushort* Wpt = Qb;                    // written after attn consumed Qb
    ushort* Xb  = (ushort*)d_out;        // d_out as scratch, overwritten by proj

    hipLaunchKernelGGL(conv_bf16, dim3(4096), dim3(256), 0, stream, x, Xb);
    hipLaunchKernelGGL(transpose_w, dim3(48, 16), dim3(256), 0, stream, W_qkv, Wqt, 3 * DM);
    hipLaunchKernelGGL(qkv_mfma, dim3(24, 64), dim3(256), 0, stream,
                       Xb, Wqt, b_qkv, Qb, Kb, Vt);
    hipLaunchKernelGGL(attn_mfma, dim3(T_SEQ / 128, 4 * NH), dim3(256), 0, stream,
                       Qb, Kb, Vt, AO);
    hipLaunchKernelGGL(transpose_w, dim3(16, 16), dim3(256), 0, stream, W_proj, Wpt, DM);
    hipLaunchKernelGGL(proj_mfma, dim3(8, 64), dim3(256), 0, stream,
                       AO, Wpt, b_proj, out);
}

// Round 6
// 204.207 us; speedup vs baseline: 13.3234x; 1.4736x over previous
//
#include <hip/hip_runtime.h>
#include <hip/hip_bf16.h>

#define NH 16
#define HD 64
#define T_SEQ 2048
#define DM 1024

typedef __attribute__((ext_vector_type(8))) short short8;
typedef __attribute__((ext_vector_type(4))) short sh4;
typedef __attribute__((ext_vector_type(4))) float f32x4;
typedef unsigned short ushort;

static __device__ __forceinline__ float bf2f(short u) {
    unsigned int x = ((unsigned int)(unsigned short)u) << 16;
    union { unsigned int i; float f; } c; c.i = x; return c.f;
}
static __device__ __forceinline__ ushort f2bf(float f) {
    union { float f; unsigned int u; } c; c.f = f;
    unsigned int r = (c.u + 0x7fffu + ((c.u >> 16) & 1u)) >> 16;
    return (ushort)r;
}

// ---------------- conversion: f32 -> bf16 (vectorized) ----------------
__global__ __launch_bounds__(256) void conv_bf16(const float* __restrict__ src,
                                                 ushort* __restrict__ dst) {
    int i = blockIdx.x * 256 + threadIdx.x;
    const float* s = src + (size_t)i * 8;
    float4 a = *(const float4*)(s);
    float4 b = *(const float4*)(s + 4);
    short8 o;
    o[0] = f2bf(a.x); o[1] = f2bf(a.y); o[2] = f2bf(a.z); o[3] = f2bf(a.w);
    o[4] = f2bf(b.x); o[5] = f2bf(b.y); o[6] = f2bf(b.z); o[7] = f2bf(b.w);
    *(short8*)(dst + (size_t)i * 8) = o;
}

// ---------------- transpose + convert: W[1024][N] f32 -> Wt[N][1024] bf16 ----------------
__global__ __launch_bounds__(256) void transpose_w(const float* __restrict__ W,
                                                   ushort* __restrict__ Wt, int N) {
    __shared__ float Ts[64][65];
    const int n0 = blockIdx.x * 64, k0 = blockIdx.y * 64;
    const int tid = threadIdx.x;
    const int cg = tid & 15, r4 = tid >> 4;
    #pragma unroll
    for (int i = 0; i < 4; ++i) {
        int r = r4 + i * 16;
        float4 v = *(const float4*)(W + (size_t)(k0 + r) * N + n0 + cg * 4);
        Ts[r][cg * 4 + 0] = v.x; Ts[r][cg * 4 + 1] = v.y;
        Ts[r][cg * 4 + 2] = v.z; Ts[r][cg * 4 + 3] = v.w;
    }
    __syncthreads();
    #pragma unroll
    for (int i = 0; i < 4; ++i) {
        int r = r4 + i * 16;
        sh4 o;
        o[0] = (short)f2bf(Ts[cg * 4 + 0][r]);
        o[1] = (short)f2bf(Ts[cg * 4 + 1][r]);
        o[2] = (short)f2bf(Ts[cg * 4 + 2][r]);
        o[3] = (short)f2bf(Ts[cg * 4 + 3][r]);
        *(sh4*)(Wt + (size_t)(n0 + r) * DM + k0 + cg * 4) = o;
    }
}

// ---------------- MFMA GEMM core (unchanged) ----------------
static __device__ __forceinline__ void gemm_core(
    const ushort* __restrict__ A, const ushort* __restrict__ Bt,
    ushort* __restrict__ As, ushort* __restrict__ Bs,
    int m0, int n0, f32x4 acc[4][4])
{
    const int tid = threadIdx.x;
    const int wid = tid >> 6, lane = tid & 63;
    const int lr = lane & 15, g = lane >> 4;
    const int wm = wid >> 1, wn = wid & 1;

    int cdst[4];
    #pragma unroll
    for (int i = 0; i < 4; ++i) {
        int c = i * 256 + tid;
        int row = c >> 3, slot = c & 7;
        cdst[i] = row * 64 + ((slot ^ (row & 7)) * 8);
    }

    short8 la[4], lb[4];
    #pragma unroll
    for (int i = 0; i < 4; ++i) {
        int c = i * 256 + tid; int row = c >> 3, slot = c & 7;
        la[i] = *(const short8*)(A + (size_t)(m0 + row) * DM + slot * 8);
        lb[i] = *(const short8*)(Bt + (size_t)(n0 + row) * DM + slot * 8);
    }

    for (int kt = 0; kt < 16; ++kt) {
        __syncthreads();
        #pragma unroll
        for (int i = 0; i < 4; ++i) {
            *(short8*)(As + cdst[i]) = la[i];
            *(short8*)(Bs + cdst[i]) = lb[i];
        }
        __syncthreads();
        if (kt < 15) {
            const int k0 = (kt + 1) * 64;
            #pragma unroll
            for (int i = 0; i < 4; ++i) {
                int c = i * 256 + tid; int row = c >> 3, slot = c & 7;
                la[i] = *(const short8*)(A + (size_t)(m0 + row) * DM + k0 + slot * 8);
                lb[i] = *(const short8*)(Bt + (size_t)(n0 + row) * DM + k0 + slot * 8);
            }
        }
        #pragma unroll
        for (int ks = 0; ks < 2; ++ks) {
            short8 af[4], bfr[4];
            #pragma unroll
            for (int mi = 0; mi < 4; ++mi) {
                int row = wm * 64 + mi * 16 + lr;
                af[mi] = *(const short8*)(As + row * 64 + (((ks * 4 + g) ^ (row & 7)) * 8));
            }
            #pragma unroll
            for (int ni = 0; ni < 4; ++ni) {
                int row = wn * 64 + ni * 16 + lr;
                bfr[ni] = *(const short8*)(Bs + row * 64 + (((ks * 4 + g) ^ (row & 7)) * 8));
            }
            #pragma unroll
            for (int mi = 0; mi < 4; ++mi)
                #pragma unroll
                for (int ni = 0; ni < 4; ++ni)
                    acc[mi][ni] = __builtin_amdgcn_mfma_f32_16x16x32_bf16(af[mi], bfr[ni], acc[mi][ni], 0, 0, 0);
        }
    }
}

// ---------------- Kernel 1: QKV GEMM (unchanged) ----------------
__global__ __launch_bounds__(256) void qkv_mfma(
    const ushort* __restrict__ Xb, const ushort* __restrict__ Wqt,
    const float* __restrict__ bias,
    ushort* __restrict__ Qb, ushort* __restrict__ Kb, ushort* __restrict__ Vt)
{
    __shared__ __align__(16) ushort smem[16384];
    ushort* As = smem; ushort* Bs = smem + 8192;
    const int m0 = blockIdx.y * 128;
    const int n0 = blockIdx.x * 128;
    f32x4 acc[4][4] = {};
    gemm_core(Xb, Wqt, As, Bs, m0, n0, acc);

    const int tid = threadIdx.x;
    const int wid = tid >> 6, lane = tid & 63;
    const int lr = lane & 15, g = lane >> 4;
    const int wm = wid >> 1, wn = wid & 1;
    const int which = n0 >> 10;
    const int bq = m0 >> 11;

    if (which < 2) {
        ushort* dst = which ? Kb : Qb;
        const float sc = which ? 1.0f : 0.125f;
        #pragma unroll
        for (int ni = 0; ni < 4; ++ni) {
            int nn = n0 + wn * 64 + ni * 16 + lr;
            const float bv = bias[nn];
            const int hh = (nn & 1023) >> 6, dd = nn & 63;
            const size_t hb = ((size_t)(bq * NH + hh)) * T_SEQ;
            #pragma unroll
            for (int mi = 0; mi < 4; ++mi)
                #pragma unroll
                for (int r = 0; r < 4; ++r) {
                    int t = (m0 + wm * 64 + mi * 16 + g * 4 + r) & 2047;
                    dst[(hb + t) * HD + dd] = f2bf((acc[mi][ni][r] + bv) * sc);
                }
        }
    } else {
        __syncthreads();
        ushort* Ct = smem;
        #pragma unroll
        for (int ni = 0; ni < 4; ++ni) {
            int lcol = wn * 64 + ni * 16 + lr;
            const float bv = bias[n0 + lcol];
            #pragma unroll
            for (int mi = 0; mi < 4; ++mi)
                #pragma unroll
                for (int r = 0; r < 4; ++r)
                    Ct[(wm * 64 + mi * 16 + g * 4 + r) * 128 + lcol] = f2bf(acc[mi][ni][r] + bv);
        }
        __syncthreads();
        const int dloc = tid >> 1, th = (tid & 1) * 64;
        const int nn = (n0 & 1023) + dloc;
        ushort* dst = Vt + ((size_t)(bq * 1024 + nn)) * T_SEQ + (m0 & 2047) + th;
        #pragma unroll
        for (int e8 = 0; e8 < 8; ++e8) {
            short8 v;
            #pragma unroll
            for (int u = 0; u < 8; ++u) v[u] = (short)Ct[(th + e8 * 8 + u) * 128 + dloc];
            *(short8*)(dst + e8 * 8) = v;
        }
    }
}

// ---------------- Kernel 3: output projection (unchanged) ----------------
__global__ __launch_bounds__(256) void proj_mfma(
    const ushort* __restrict__ AO, const ushort* __restrict__ Wpt,
    const float* __restrict__ bias, float* __restrict__ Y)
{
    __shared__ __align__(16) ushort smem[16384];
    const int m0 = blockIdx.y * 128;
    const int n0 = blockIdx.x * 128;
    f32x4 acc[4][4] = {};
    gemm_core(AO, Wpt, smem, smem + 8192, m0, n0, acc);

    const int tid = threadIdx.x;
    const int wid = tid >> 6, lane = tid & 63;
    const int lr = lane & 15, g = lane >> 4;
    const int wm = wid >> 1, wn = wid & 1;
    #pragma unroll
    for (int ni = 0; ni < 4; ++ni) {
        int nn = n0 + wn * 64 + ni * 16 + lr;
        const float bv = bias[nn];
        #pragma unroll
        for (int mi = 0; mi < 4; ++mi)
            #pragma unroll
            for (int r = 0; r < 4; ++r) {
                int m = m0 + wm * 64 + mi * 16 + g * 4 + r;
                Y[(size_t)m * DM + nn] = acc[mi][ni][r] + bv;
            }
    }
}

// ---------------- Kernel 2: swapped-QK^T flash attention, dbuf + uniform blocks ----------------
// Block = (sid, bh): processes q-strips j=sid and j=15-sid  -> uniform 36 tiles/block.
// K/V double-buffered in LDS; loads issued one tile ahead into regs (latency hidden).
__global__ __launch_bounds__(256) void attn_mfma(
    const ushort* __restrict__ Qb,   // [bh][t][64], pre-scaled by 1/8
    const ushort* __restrict__ Kb,   // [bh][t][64]
    const ushort* __restrict__ Vt,   // [bh][d][2048]
    ushort* __restrict__ AO)         // [b*2048 + t][1024] bf16
{
    __shared__ __align__(16) ushort Ks[2][4096];
    __shared__ __align__(16) ushort Vs[2][4096];   // [d][k], swizzled

    const int bh = blockIdx.y;
    const int sid = blockIdx.x;                    // 0..7
    const int tid = threadIdx.x;
    const int wid = tid >> 6;
    const int lane = tid & 63;
    const int lr = lane & 15;
    const int g = lane >> 4;

    const ushort* Kg = Kb + (size_t)bh * T_SEQ * HD;
    const ushort* Vg = Vt + (size_t)bh * HD * T_SEQ;

    // staging geometry: thread covers rows {srow, srow+32}, 8 bf16 cols at sco
    const int srow = tid >> 3;             // 0..31
    const int sco = (tid & 7) * 8;
    const int ssw = sco ^ ((srow & 7) << 3);
    const int sdst0 = srow * 64 + ssw;
    const int sdst1 = (srow + 32) * 64 + ssw;

    const int srcA = ((lane >> 4) & 1) * 32 + lr;
    const int srcB = srcA + 16;
    const bool selhi = (lane >> 5) != 0;

    const int b = bh >> 4, h = bh & 15;
    ushort* AOg = AO + (size_t)b * T_SEQ * DM + h * HD;

    #pragma unroll 1
    for (int half = 0; half < 2; ++half) {
        const int j = half ? (15 - sid) : sid;
        const int q0 = j * 128;
        const int qlo = q0 + wid * 32;
        const int ntiles = 2 * j + 2;

        // Q fragments (B-operand)
        short8 qb[2][2];
        {
            const ushort* Qg = Qb + ((size_t)bh * T_SEQ + qlo) * HD;
            #pragma unroll
            for (int qi = 0; qi < 2; ++qi)
                #pragma unroll
                for (int ks = 0; ks < 2; ++ks)
                    qb[qi][ks] = *(const short8*)(Qg + (size_t)(qi * 16 + lr) * HD + ks * 32 + g * 8);
        }

        f32x4 po[2][4] = {};
        float mrun[2] = {-INFINITY, -INFINITY};
        float lrun[2] = {0.f, 0.f};

        // prologue: tile 0 -> regs -> LDS[0]; tile 1 -> regs
        short8 rk0, rk1, rv0, rv1;
        rk0 = *(const short8*)(Kg + (size_t)srow * HD + sco);
        rk1 = *(const short8*)(Kg + (size_t)(srow + 32) * HD + sco);
        rv0 = *(const short8*)(Vg + (size_t)srow * T_SEQ + sco);
        rv1 = *(const short8*)(Vg + (size_t)(srow + 32) * T_SEQ + sco);
        *(short8*)(&Ks[0][sdst0]) = rk0;  *(short8*)(&Ks[0][sdst1]) = rk1;
        *(short8*)(&Vs[0][sdst0]) = rv0;  *(short8*)(&Vs[0][sdst1]) = rv1;
        {
            const int nk0 = 64;
            rk0 = *(const short8*)(Kg + (size_t)(nk0 + srow) * HD + sco);
            rk1 = *(const short8*)(Kg + (size_t)(nk0 + srow + 32) * HD + sco);
            rv0 = *(const short8*)(Vg + (size_t)srow * T_SEQ + nk0 + sco);
            rv1 = *(const short8*)(Vg + (size_t)(srow + 32) * T_SEQ + nk0 + sco);
        }
        __syncthreads();

        for (int tt = 0; tt < ntiles; ++tt) {
            const int k0 = tt * 64;
            const int cur = tt & 1;
            if (tt + 1 < ntiles) {
                // write next tile (loads issued one iteration ago)
                const int nxt = cur ^ 1;
                *(short8*)(&Ks[nxt][sdst0]) = rk0;  *(short8*)(&Ks[nxt][sdst1]) = rk1;
                *(short8*)(&Vs[nxt][sdst0]) = rv0;  *(short8*)(&Vs[nxt][sdst1]) = rv1;
                if (tt + 2 < ntiles) {
                    const int nk0 = (tt + 2) * 64;
                    rk0 = *(const short8*)(Kg + (size_t)(nk0 + srow) * HD + sco);
                    rk1 = *(const short8*)(Kg + (size_t)(nk0 + srow + 32) * HD + sco);
                    rv0 = *(const short8*)(Vg + (size_t)srow * T_SEQ + nk0 + sco);
                    rv1 = *(const short8*)(Vg + (size_t)(srow + 32) * T_SEQ + nk0 + sco);
                }
            }

            if (k0 <= qlo + 31) {
                const ushort* ksb = Ks[cur];
                const ushort* vsb = Vs[cur];

                // ---- S^T = mfma(K, Q)
                f32x4 sp[2][4] = {};
                __builtin_amdgcn_s_setprio(1);
                #pragma unroll
                for (int ks = 0; ks < 2; ++ks) {
                    #pragma unroll
                    for (int ki = 0; ki < 4; ++ki) {
                        int krow = ki * 16 + lr;
                        short8 kf = *(const short8*)(&ksb[krow * 64 + ((ks * 32 + g * 8) ^ ((krow & 7) << 3))]);
                        sp[0][ki] = __builtin_amdgcn_mfma_f32_16x16x32_bf16(kf, qb[0][ks], sp[0][ki], 0, 0, 0);
                        sp[1][ki] = __builtin_amdgcn_mfma_f32_16x16x32_bf16(kf, qb[1][ks], sp[1][ki], 0, 0, 0);
                    }
                }
                __builtin_amdgcn_s_setprio(0);

                const bool needmask = (k0 + 63 > qlo);

                #pragma unroll
                for (int qi = 0; qi < 2; ++qi) {
                    const int q = qlo + qi * 16 + lr;
                    if (needmask) {
                        const int lim = q - k0 - 4 * g;
                        #pragma unroll
                        for (int ki = 0; ki < 4; ++ki)
                            #pragma unroll
                            for (int r = 0; r < 4; ++r)
                                sp[qi][ki][r] = (ki * 16 + r <= lim) ? sp[qi][ki][r] : -INFINITY;
                    }
                    float tmax = -INFINITY;
                    #pragma unroll
                    for (int ki = 0; ki < 4; ++ki)
                        #pragma unroll
                        for (int r = 0; r < 4; ++r) tmax = fmaxf(tmax, sp[qi][ki][r]);
                    tmax = fmaxf(tmax, __shfl_xor(tmax, 16));
                    tmax = fmaxf(tmax, __shfl_xor(tmax, 32));
                    const float mold = mrun[qi];
                    const float mnew = fmaxf(mold, tmax);
                    const float corr = __expf(mold - mnew);
                    float rs = 0.f;
                    #pragma unroll
                    for (int ki = 0; ki < 4; ++ki)
                        #pragma unroll
                        for (int r = 0; r < 4; ++r) {
                            float p = __expf(sp[qi][ki][r] - mnew);
                            sp[qi][ki][r] = p;
                            rs += p;
                        }
                    rs += __shfl_xor(rs, 16);
                    rs += __shfl_xor(rs, 32);
                    lrun[qi] = lrun[qi] * corr + rs;
                    mrun[qi] = mnew;
                    #pragma unroll
                    for (int di = 0; di < 4; ++di)
                        #pragma unroll
                        for (int r = 0; r < 4; ++r) po[qi][di][r] *= corr;
                }

                // ---- repack P^T in-register, accumulate O^T = mfma(V^T, P^T)
                #pragma unroll
                for (int qi = 0; qi < 2; ++qi) {
                    unsigned int u[4][2];
                    #pragma unroll
                    for (int ki = 0; ki < 4; ++ki) {
                        asm("v_cvt_pk_bf16_f32 %0, %1, %2"
                            : "=v"(u[ki][0]) : "v"(sp[qi][ki][0]), "v"(sp[qi][ki][1]));
                        asm("v_cvt_pk_bf16_f32 %0, %1, %2"
                            : "=v"(u[ki][1]) : "v"(sp[qi][ki][2]), "v"(sp[qi][ki][3]));
                    }
                    #pragma unroll
                    for (int ks = 0; ks < 2; ++ks) {
                        const int a0 = (int)u[2 * ks][0],     a1 = (int)u[2 * ks][1];
                        const int b0 = (int)u[2 * ks + 1][0], b1 = (int)u[2 * ks + 1][1];
                        const int lo0 = __shfl(a0, srcA), lo1 = __shfl(a1, srcA);
                        const int lo2 = __shfl(a0, srcB), lo3 = __shfl(a1, srcB);
                        const int hi0 = __shfl(b0, srcA), hi1 = __shfl(b1, srcA);
                        const int hi2 = __shfl(b0, srcB), hi3 = __shfl(b1, srcB);
                        union { int w[4]; short8 s8; } pb;
                        pb.w[0] = selhi ? hi0 : lo0;
                        pb.w[1] = selhi ? hi1 : lo1;
                        pb.w[2] = selhi ? hi2 : lo2;
                        pb.w[3] = selhi ? hi3 : lo3;
                        const int koff = (ks * 32 + g * 8);
                        __builtin_amdgcn_s_setprio(1);
                        #pragma unroll
                        for (int di = 0; di < 4; ++di) {
                            int vrow = di * 16 + lr;
                            short8 vf = *(const short8*)(&vsb[vrow * 64 + (koff ^ ((vrow & 7) << 3))]);
                            po[0][di] = (qi == 0)
                                ? __builtin_amdgcn_mfma_f32_16x16x32_bf16(vf, pb.s8, po[0][di], 0, 0, 0)
                                : po[0][di];
                            po[1][di] = (qi == 1)
                                ? __builtin_amdgcn_mfma_f32_16x16x32_bf16(vf, pb.s8, po[1][di], 0, 0, 0)
                                : po[1][di];
                        }
                        __builtin_amdgcn_s_setprio(0);
                    }
                }
            }
            __syncthreads();
        }

        // ---- epilogue for this strip
        #pragma unroll
        for (int qi = 0; qi < 2; ++qi) {
            const float inv = 1.f / lrun[qi];
            const int q = qlo + qi * 16 + lr;
            #pragma unroll
            for (int di = 0; di < 4; ++di) {
                unsigned int w0, w1;
                float f0 = po[qi][di][0] * inv, f1 = po[qi][di][1] * inv;
                float f2 = po[qi][di][2] * inv, f3 = po[qi][di][3] * inv;
                asm("v_cvt_pk_bf16_f32 %0, %1, %2" : "=v"(w0) : "v"(f0), "v"(f1));
                asm("v_cvt_pk_bf16_f32 %0, %1, %2" : "=v"(w1) : "v"(f2), "v"(f3));
                uint2 wv; wv.x = w0; wv.y = w1;
                *(uint2*)(AOg + (size_t)q * DM + di * 16 + g * 4) = wv;
            }
        }
    }
}

extern "C" void kernel_launch(void* const* d_in, const int* in_sizes, int n_in,
                              void* d_out, int out_size, void* d_ws, size_t ws_size,
                              hipStream_t stream) {
    const float* x      = (const float*)d_in[0];
    const float* W_qkv  = (const float*)d_in[1];
    const float* b_qkv  = (const float*)d_in[2];
    const float* W_proj = (const float*)d_in[3];
    const float* b_proj = (const float*)d_in[4];
    float* out = (float*)d_out;

    const size_t perbuf = (size_t)4 * NH * T_SEQ * HD;
    ushort* Qb  = (ushort*)d_ws;
    ushort* Kb  = Qb + perbuf;
    ushort* Vt  = Kb + perbuf;
    ushort* AO  = Vt + perbuf;
    ushort* Wqt = AO;                    // consumed by qkv_mfma before attn writes AO
    ushort* Wpt = Qb;                    // written after attn consumed Qb
    ushort* Xb  = (ushort*)d_out;        // d_out as scratch, overwritten by proj

    hipLaunchKernelGGL(conv_bf16, dim3(4096), dim3(256), 0, stream, x, Xb);
    hipLaunchKernelGGL(transpose_w, dim3(48, 16), dim3(256), 0, stream, W_qkv, Wqt, 3 * DM);
    hipLaunchKernelGGL(qkv_mfma, dim3(24, 64), dim3(256), 0, stream,
                       Xb, Wqt, b_qkv, Qb, Kb, Vt);
    hipLaunchKernelGGL(attn_mfma, dim3(8, 4 * NH), dim3(256), 0, stream,
                       Qb, Kb, Vt, AO);
    hipLaunchKernelGGL(transpose_w, dim3(16, 16), dim3(256), 0, stream, W_proj, Wpt, DM);
    hipLaunchKernelGGL(proj_mfma, dim3(8, 64), dim3(256), 0, stream,
                       AO, Wpt, b_proj, out);
}

// Round 7
// 201.683 us; speedup vs baseline: 13.4902x; 1.0125x over previous
//
#include <hip/hip_runtime.h>
#include <hip/hip_bf16.h>

#define NH 16
#define HD 64
#define T_SEQ 2048
#define DM 1024

typedef __attribute__((ext_vector_type(8))) short short8;
typedef __attribute__((ext_vector_type(4))) short sh4;
typedef __attribute__((ext_vector_type(4))) float f32x4;
typedef unsigned short ushort;

static __device__ __forceinline__ float bf2f(short u) {
    unsigned int x = ((unsigned int)(unsigned short)u) << 16;
    union { unsigned int i; float f; } c; c.i = x; return c.f;
}
static __device__ __forceinline__ ushort f2bf(float f) {
    union { float f; unsigned int u; } c; c.f = f;
    unsigned int r = (c.u + 0x7fffu + ((c.u >> 16) & 1u)) >> 16;
    return (ushort)r;
}

// ---------------- conversion: f32 -> bf16 (vectorized) ----------------
__global__ __launch_bounds__(256) void conv_bf16(const float* __restrict__ src,
                                                 ushort* __restrict__ dst) {
    int i = blockIdx.x * 256 + threadIdx.x;
    const float* s = src + (size_t)i * 8;
    float4 a = *(const float4*)(s);
    float4 b = *(const float4*)(s + 4);
    short8 o;
    o[0] = f2bf(a.x); o[1] = f2bf(a.y); o[2] = f2bf(a.z); o[3] = f2bf(a.w);
    o[4] = f2bf(b.x); o[5] = f2bf(b.y); o[6] = f2bf(b.z); o[7] = f2bf(b.w);
    *(short8*)(dst + (size_t)i * 8) = o;
}

// ---------------- transpose + convert: W[1024][N] f32 -> Wt[N][1024] bf16 ----------------
__global__ __launch_bounds__(256) void transpose_w(const float* __restrict__ W,
                                                   ushort* __restrict__ Wt, int N) {
    __shared__ float Ts[64][65];
    const int n0 = blockIdx.x * 64, k0 = blockIdx.y * 64;
    const int tid = threadIdx.x;
    const int cg = tid & 15, r4 = tid >> 4;
    #pragma unroll
    for (int i = 0; i < 4; ++i) {
        int r = r4 + i * 16;
        float4 v = *(const float4*)(W + (size_t)(k0 + r) * N + n0 + cg * 4);
        Ts[r][cg * 4 + 0] = v.x; Ts[r][cg * 4 + 1] = v.y;
        Ts[r][cg * 4 + 2] = v.z; Ts[r][cg * 4 + 3] = v.w;
    }
    __syncthreads();
    #pragma unroll
    for (int i = 0; i < 4; ++i) {
        int r = r4 + i * 16;
        sh4 o;
        o[0] = (short)f2bf(Ts[cg * 4 + 0][r]);
        o[1] = (short)f2bf(Ts[cg * 4 + 1][r]);
        o[2] = (short)f2bf(Ts[cg * 4 + 2][r]);
        o[3] = (short)f2bf(Ts[cg * 4 + 3][r]);
        *(sh4*)(Wt + (size_t)(n0 + r) * DM + k0 + cg * 4) = o;
    }
}

// ---------------- MFMA GEMM core (unchanged) ----------------
static __device__ __forceinline__ void gemm_core(
    const ushort* __restrict__ A, const ushort* __restrict__ Bt,
    ushort* __restrict__ As, ushort* __restrict__ Bs,
    int m0, int n0, f32x4 acc[4][4])
{
    const int tid = threadIdx.x;
    const int wid = tid >> 6, lane = tid & 63;
    const int lr = lane & 15, g = lane >> 4;
    const int wm = wid >> 1, wn = wid & 1;

    int cdst[4];
    #pragma unroll
    for (int i = 0; i < 4; ++i) {
        int c = i * 256 + tid;
        int row = c >> 3, slot = c & 7;
        cdst[i] = row * 64 + ((slot ^ (row & 7)) * 8);
    }

    short8 la[4], lb[4];
    #pragma unroll
    for (int i = 0; i < 4; ++i) {
        int c = i * 256 + tid; int row = c >> 3, slot = c & 7;
        la[i] = *(const short8*)(A + (size_t)(m0 + row) * DM + slot * 8);
        lb[i] = *(const short8*)(Bt + (size_t)(n0 + row) * DM + slot * 8);
    }

    for (int kt = 0; kt < 16; ++kt) {
        __syncthreads();
        #pragma unroll
        for (int i = 0; i < 4; ++i) {
            *(short8*)(As + cdst[i]) = la[i];
            *(short8*)(Bs + cdst[i]) = lb[i];
        }
        __syncthreads();
        if (kt < 15) {
            const int k0 = (kt + 1) * 64;
            #pragma unroll
            for (int i = 0; i < 4; ++i) {
                int c = i * 256 + tid; int row = c >> 3, slot = c & 7;
                la[i] = *(const short8*)(A + (size_t)(m0 + row) * DM + k0 + slot * 8);
                lb[i] = *(const short8*)(Bt + (size_t)(n0 + row) * DM + k0 + slot * 8);
            }
        }
        #pragma unroll
        for (int ks = 0; ks < 2; ++ks) {
            short8 af[4], bfr[4];
            #pragma unroll
            for (int mi = 0; mi < 4; ++mi) {
                int row = wm * 64 + mi * 16 + lr;
                af[mi] = *(const short8*)(As + row * 64 + (((ks * 4 + g) ^ (row & 7)) * 8));
            }
            #pragma unroll
            for (int ni = 0; ni < 4; ++ni) {
                int row = wn * 64 + ni * 16 + lr;
                bfr[ni] = *(const short8*)(Bs + row * 64 + (((ks * 4 + g) ^ (row & 7)) * 8));
            }
            #pragma unroll
            for (int mi = 0; mi < 4; ++mi)
                #pragma unroll
                for (int ni = 0; ni < 4; ++ni)
                    acc[mi][ni] = __builtin_amdgcn_mfma_f32_16x16x32_bf16(af[mi], bfr[ni], acc[mi][ni], 0, 0, 0);
        }
    }
}

// ---------------- Kernel 1: QKV GEMM (unchanged) ----------------
__global__ __launch_bounds__(256) void qkv_mfma(
    const ushort* __restrict__ Xb, const ushort* __restrict__ Wqt,
    const float* __restrict__ bias,
    ushort* __restrict__ Qb, ushort* __restrict__ Kb, ushort* __restrict__ Vt)
{
    __shared__ __align__(16) ushort smem[16384];
    ushort* As = smem; ushort* Bs = smem + 8192;
    const int m0 = blockIdx.y * 128;
    const int n0 = blockIdx.x * 128;
    f32x4 acc[4][4] = {};
    gemm_core(Xb, Wqt, As, Bs, m0, n0, acc);

    const int tid = threadIdx.x;
    const int wid = tid >> 6, lane = tid & 63;
    const int lr = lane & 15, g = lane >> 4;
    const int wm = wid >> 1, wn = wid & 1;
    const int which = n0 >> 10;
    const int bq = m0 >> 11;

    if (which < 2) {
        ushort* dst = which ? Kb : Qb;
        const float sc = which ? 1.0f : 0.125f;
        #pragma unroll
        for (int ni = 0; ni < 4; ++ni) {
            int nn = n0 + wn * 64 + ni * 16 + lr;
            const float bv = bias[nn];
            const int hh = (nn & 1023) >> 6, dd = nn & 63;
            const size_t hb = ((size_t)(bq * NH + hh)) * T_SEQ;
            #pragma unroll
            for (int mi = 0; mi < 4; ++mi)
                #pragma unroll
                for (int r = 0; r < 4; ++r) {
                    int t = (m0 + wm * 64 + mi * 16 + g * 4 + r) & 2047;
                    dst[(hb + t) * HD + dd] = f2bf((acc[mi][ni][r] + bv) * sc);
                }
        }
    } else {
        __syncthreads();
        ushort* Ct = smem;
        #pragma unroll
        for (int ni = 0; ni < 4; ++ni) {
            int lcol = wn * 64 + ni * 16 + lr;
            const float bv = bias[n0 + lcol];
            #pragma unroll
            for (int mi = 0; mi < 4; ++mi)
                #pragma unroll
                for (int r = 0; r < 4; ++r)
                    Ct[(wm * 64 + mi * 16 + g * 4 + r) * 128 + lcol] = f2bf(acc[mi][ni][r] + bv);
        }
        __syncthreads();
        const int dloc = tid >> 1, th = (tid & 1) * 64;
        const int nn = (n0 & 1023) + dloc;
        ushort* dst = Vt + ((size_t)(bq * 1024 + nn)) * T_SEQ + (m0 & 2047) + th;
        #pragma unroll
        for (int e8 = 0; e8 < 8; ++e8) {
            short8 v;
            #pragma unroll
            for (int u = 0; u < 8; ++u) v[u] = (short)Ct[(th + e8 * 8 + u) * 128 + dloc];
            *(short8*)(dst + e8 * 8) = v;
        }
    }
}

// ---------------- Kernel 3: output projection (unchanged) ----------------
__global__ __launch_bounds__(256) void proj_mfma(
    const ushort* __restrict__ AO, const ushort* __restrict__ Wpt,
    const float* __restrict__ bias, float* __restrict__ Y)
{
    __shared__ __align__(16) ushort smem[16384];
    const int m0 = blockIdx.y * 128;
    const int n0 = blockIdx.x * 128;
    f32x4 acc[4][4] = {};
    gemm_core(AO, Wpt, smem, smem + 8192, m0, n0, acc);

    const int tid = threadIdx.x;
    const int wid = tid >> 6, lane = tid & 63;
    const int lr = lane & 15, g = lane >> 4;
    const int wm = wid >> 1, wn = wid & 1;
    #pragma unroll
    for (int ni = 0; ni < 4; ++ni) {
        int nn = n0 + wn * 64 + ni * 16 + lr;
        const float bv = bias[nn];
        #pragma unroll
        for (int mi = 0; mi < 4; ++mi)
            #pragma unroll
            for (int r = 0; r < 4; ++r) {
                int m = m0 + wm * 64 + mi * 16 + g * 4 + r;
                Y[(size_t)m * DM + nn] = acc[mi][ni][r] + bv;
            }
    }
}

// ---------------- Kernel 2: swapped-QK^T flash attention, dbuf, 1 strip/block ----------------
// Grid (64 bh, 16 strips); j = 15 - blockIdx.y  -> heavy strips dispatched first (LPT).
// 1024 blocks -> 4 blocks/CU resident (VGPR 112, LDS 32KB allow it).
__global__ __launch_bounds__(256) void attn_mfma(
    const ushort* __restrict__ Qb,   // [bh][t][64], pre-scaled by 1/8
    const ushort* __restrict__ Kb,   // [bh][t][64]
    const ushort* __restrict__ Vt,   // [bh][d][2048]
    ushort* __restrict__ AO)         // [b*2048 + t][1024] bf16
{
    __shared__ __align__(16) ushort Ks[2][4096];
    __shared__ __align__(16) ushort Vs[2][4096];   // [d][k], swizzled

    const int bh = blockIdx.x;
    const int j = 15 - blockIdx.y;                 // heavy-first
    const int tid = threadIdx.x;
    const int wid = tid >> 6;
    const int lane = tid & 63;
    const int lr = lane & 15;
    const int g = lane >> 4;

    const ushort* Kg = Kb + (size_t)bh * T_SEQ * HD;
    const ushort* Vg = Vt + (size_t)bh * HD * T_SEQ;

    const int srow = tid >> 3;             // 0..31
    const int sco = (tid & 7) * 8;
    const int ssw = sco ^ ((srow & 7) << 3);
    const int sdst0 = srow * 64 + ssw;
    const int sdst1 = (srow + 32) * 64 + ssw;

    const int srcA = ((lane >> 4) & 1) * 32 + lr;
    const int srcB = srcA + 16;
    const bool selhi = (lane >> 5) != 0;

    const int b = bh >> 4, h = bh & 15;
    ushort* AOg = AO + (size_t)b * T_SEQ * DM + h * HD;

    const int q0 = j * 128;
    const int qlo = q0 + wid * 32;
    const int ntiles = 2 * j + 2;

    // Q fragments (B-operand)
    short8 qb[2][2];
    {
        const ushort* Qg = Qb + ((size_t)bh * T_SEQ + qlo) * HD;
        #pragma unroll
        for (int qi = 0; qi < 2; ++qi)
            #pragma unroll
            for (int ks = 0; ks < 2; ++ks)
                qb[qi][ks] = *(const short8*)(Qg + (size_t)(qi * 16 + lr) * HD + ks * 32 + g * 8);
    }

    f32x4 po[2][4] = {};
    float mrun[2] = {-INFINITY, -INFINITY};
    float lrun[2] = {0.f, 0.f};

    // prologue: tile 0 -> regs -> LDS[0]; tile 1 -> regs
    short8 rk0, rk1, rv0, rv1;
    rk0 = *(const short8*)(Kg + (size_t)srow * HD + sco);
    rk1 = *(const short8*)(Kg + (size_t)(srow + 32) * HD + sco);
    rv0 = *(const short8*)(Vg + (size_t)srow * T_SEQ + sco);
    rv1 = *(const short8*)(Vg + (size_t)(srow + 32) * T_SEQ + sco);
    *(short8*)(&Ks[0][sdst0]) = rk0;  *(short8*)(&Ks[0][sdst1]) = rk1;
    *(short8*)(&Vs[0][sdst0]) = rv0;  *(short8*)(&Vs[0][sdst1]) = rv1;
    {
        const int nk0 = 64;
        rk0 = *(const short8*)(Kg + (size_t)(nk0 + srow) * HD + sco);
        rk1 = *(const short8*)(Kg + (size_t)(nk0 + srow + 32) * HD + sco);
        rv0 = *(const short8*)(Vg + (size_t)srow * T_SEQ + nk0 + sco);
        rv1 = *(const short8*)(Vg + (size_t)(srow + 32) * T_SEQ + nk0 + sco);
    }
    __syncthreads();

    for (int tt = 0; tt < ntiles; ++tt) {
        const int k0 = tt * 64;
        const int cur = tt & 1;
        if (tt + 1 < ntiles) {
            const int nxt = cur ^ 1;
            *(short8*)(&Ks[nxt][sdst0]) = rk0;  *(short8*)(&Ks[nxt][sdst1]) = rk1;
            *(short8*)(&Vs[nxt][sdst0]) = rv0;  *(short8*)(&Vs[nxt][sdst1]) = rv1;
            if (tt + 2 < ntiles) {
                const int nk0 = (tt + 2) * 64;
                rk0 = *(const short8*)(Kg + (size_t)(nk0 + srow) * HD + sco);
                rk1 = *(const short8*)(Kg + (size_t)(nk0 + srow + 32) * HD + sco);
                rv0 = *(const short8*)(Vg + (size_t)srow * T_SEQ + nk0 + sco);
                rv1 = *(const short8*)(Vg + (size_t)(srow + 32) * T_SEQ + nk0 + sco);
            }
        }

        if (k0 <= qlo + 31) {
            const ushort* ksb = Ks[cur];
            const ushort* vsb = Vs[cur];

            // ---- S^T = mfma(K, Q)
            f32x4 sp[2][4] = {};
            __builtin_amdgcn_s_setprio(1);
            #pragma unroll
            for (int ks = 0; ks < 2; ++ks) {
                #pragma unroll
                for (int ki = 0; ki < 4; ++ki) {
                    int krow = ki * 16 + lr;
                    short8 kf = *(const short8*)(&ksb[krow * 64 + ((ks * 32 + g * 8) ^ ((krow & 7) << 3))]);
                    sp[0][ki] = __builtin_amdgcn_mfma_f32_16x16x32_bf16(kf, qb[0][ks], sp[0][ki], 0, 0, 0);
                    sp[1][ki] = __builtin_amdgcn_mfma_f32_16x16x32_bf16(kf, qb[1][ks], sp[1][ki], 0, 0, 0);
                }
            }
            __builtin_amdgcn_s_setprio(0);

            const bool needmask = (k0 + 63 > qlo);

            #pragma unroll
            for (int qi = 0; qi < 2; ++qi) {
                const int q = qlo + qi * 16 + lr;
                if (needmask) {
                    const int lim = q - k0 - 4 * g;
                    #pragma unroll
                    for (int ki = 0; ki < 4; ++ki)
                        #pragma unroll
                        for (int r = 0; r < 4; ++r)
                            sp[qi][ki][r] = (ki * 16 + r <= lim) ? sp[qi][ki][r] : -INFINITY;
                }
                float tmax = -INFINITY;
                #pragma unroll
                for (int ki = 0; ki < 4; ++ki)
                    #pragma unroll
                    for (int r = 0; r < 4; ++r) tmax = fmaxf(tmax, sp[qi][ki][r]);
                tmax = fmaxf(tmax, __shfl_xor(tmax, 16));
                tmax = fmaxf(tmax, __shfl_xor(tmax, 32));
                const float mold = mrun[qi];
                const float mnew = fmaxf(mold, tmax);
                const float corr = __expf(mold - mnew);
                float rs = 0.f;
                #pragma unroll
                for (int ki = 0; ki < 4; ++ki)
                    #pragma unroll
                    for (int r = 0; r < 4; ++r) {
                        float p = __expf(sp[qi][ki][r] - mnew);
                        sp[qi][ki][r] = p;
                        rs += p;
                    }
                rs += __shfl_xor(rs, 16);
                rs += __shfl_xor(rs, 32);
                lrun[qi] = lrun[qi] * corr + rs;
                mrun[qi] = mnew;
                #pragma unroll
                for (int di = 0; di < 4; ++di)
                    #pragma unroll
                    for (int r = 0; r < 4; ++r) po[qi][di][r] *= corr;
            }

            // ---- repack P^T in-register, accumulate O^T = mfma(V^T, P^T)
            #pragma unroll
            for (int qi = 0; qi < 2; ++qi) {
                unsigned int u[4][2];
                #pragma unroll
                for (int ki = 0; ki < 4; ++ki) {
                    asm("v_cvt_pk_bf16_f32 %0, %1, %2"
                        : "=v"(u[ki][0]) : "v"(sp[qi][ki][0]), "v"(sp[qi][ki][1]));
                    asm("v_cvt_pk_bf16_f32 %0, %1, %2"
                        : "=v"(u[ki][1]) : "v"(sp[qi][ki][2]), "v"(sp[qi][ki][3]));
                }
                #pragma unroll
                for (int ks = 0; ks < 2; ++ks) {
                    const int a0 = (int)u[2 * ks][0],     a1 = (int)u[2 * ks][1];
                    const int b0 = (int)u[2 * ks + 1][0], b1 = (int)u[2 * ks + 1][1];
                    const int lo0 = __shfl(a0, srcA), lo1 = __shfl(a1, srcA);
                    const int lo2 = __shfl(a0, srcB), lo3 = __shfl(a1, srcB);
                    const int hi0 = __shfl(b0, srcA), hi1 = __shfl(b1, srcA);
                    const int hi2 = __shfl(b0, srcB), hi3 = __shfl(b1, srcB);
                    union { int w[4]; short8 s8; } pb;
                    pb.w[0] = selhi ? hi0 : lo0;
                    pb.w[1] = selhi ? hi1 : lo1;
                    pb.w[2] = selhi ? hi2 : lo2;
                    pb.w[3] = selhi ? hi3 : lo3;
                    const int koff = (ks * 32 + g * 8);
                    __builtin_amdgcn_s_setprio(1);
                    #pragma unroll
                    for (int di = 0; di < 4; ++di) {
                        int vrow = di * 16 + lr;
                        short8 vf = *(const short8*)(&vsb[vrow * 64 + (koff ^ ((vrow & 7) << 3))]);
                        po[0][di] = (qi == 0)
                            ? __builtin_amdgcn_mfma_f32_16x16x32_bf16(vf, pb.s8, po[0][di], 0, 0, 0)
                            : po[0][di];
                        po[1][di] = (qi == 1)
                            ? __builtin_amdgcn_mfma_f32_16x16x32_bf16(vf, pb.s8, po[1][di], 0, 0, 0)
                            : po[1][di];
                    }
                    __builtin_amdgcn_s_setprio(0);
                }
            }
        }
        __syncthreads();
    }

    // ---- epilogue
    #pragma unroll
    for (int qi = 0; qi < 2; ++qi) {
        const float inv = 1.f / lrun[qi];
        const int q = qlo + qi * 16 + lr;
        #pragma unroll
        for (int di = 0; di < 4; ++di) {
            unsigned int w0, w1;
            float f0 = po[qi][di][0] * inv, f1 = po[qi][di][1] * inv;
            float f2 = po[qi][di][2] * inv, f3 = po[qi][di][3] * inv;
            asm("v_cvt_pk_bf16_f32 %0, %1, %2" : "=v"(w0) : "v"(f0), "v"(f1));
            asm("v_cvt_pk_bf16_f32 %0, %1, %2" : "=v"(w1) : "v"(f2), "v"(f3));
            uint2 wv; wv.x = w0; wv.y = w1;
            *(uint2*)(AOg + (size_t)q * DM + di * 16 + g * 4) = wv;
        }
    }
}

extern "C" void kernel_launch(void* const* d_in, const int* in_sizes, int n_in,
                              void* d_out, int out_size, void* d_ws, size_t ws_size,
                              hipStream_t stream) {
    const float* x      = (const float*)d_in[0];
    const float* W_qkv  = (const float*)d_in[1];
    const float* b_qkv  = (const float*)d_in[2];
    const float* W_proj = (const float*)d_in[3];
    const float* b_proj = (const float*)d_in[4];
    float* out = (float*)d_out;

    const size_t perbuf = (size_t)4 * NH * T_SEQ * HD;
    ushort* Qb  = (ushort*)d_ws;
    ushort* Kb  = Qb + perbuf;
    ushort* Vt  = Kb + perbuf;
    ushort* AO  = Vt + perbuf;
    ushort* Wqt = AO;                    // consumed by qkv_mfma before attn writes AO
    ushort* Wpt = Qb;                    // written after attn consumed Qb
    ushort* Xb  = (ushort*)d_out;        // d_out as scratch, overwritten by proj

    hipLaunchKernelGGL(conv_bf16, dim3(4096), dim3(256), 0, stream, x, Xb);
    hipLaunchKernelGGL(transpose_w, dim3(48, 16), dim3(256), 0, stream, W_qkv, Wqt, 3 * DM);
    hipLaunchKernelGGL(qkv_mfma, dim3(24, 64), dim3(256), 0, stream,
                       Xb, Wqt, b_qkv, Qb, Kb, Vt);
    hipLaunchKernelGGL(attn_mfma, dim3(64, 16), dim3(256), 0, stream,
                       Qb, Kb, Vt, AO);
    hipLaunchKernelGGL(transpose_w, dim3(16, 16), dim3(256), 0, stream, W_proj, Wpt, DM);
    hipLaunchKernelGGL(proj_mfma, dim3(8, 64), dim3(256), 0, stream,
                       AO, Wpt, b_proj, out);
}